// Round 10
// baseline (373.169 us; speedup 1.0000x reference)
//
#include <hip/hip_runtime.h>
#include <hip/hip_bf16.h>

// ModernNCA fused pipeline, v22.
// B=512 queries, N=131072 candidates, D=192, H=256, NY=10.
// v22: v20 base (v21's global-operand k_dist refuted: FETCH 15->55MB,
// WRITE 13->58MB, 61us -- LDS staging restored) + P round-trip removed
// the RIGHT way this time. v17's ACC-atomic failed on REGISTERS (16
// hoisted 64b addresses inside acc live range -> cliff/spill), not atomic
// throughput. Now: k_dist unchanged through LDS stage + barrier; then
// thread t does 11 atomicAdds for query qh+t from Pst[t*12+i] -- uniform
// base + t*64 + i*4, ~3 live VGPRs, after the acc region. i8=blockIdx&7
// is XCD-constant under the slice remap -> sub-accumulators are L2-LOCAL.
// k_comb deleted; k_norm (32 blocks) divides; k_prep zeroes ACC.
// v20: mc/nq-split acc[4][2], 112 regs, (256,4), single dispatch round.
// v19: XCD-chunked slice remap. v16: ct8 dbuf issue-early staging.
// v14: transposed-operand MFMA epilogues (dword LDS, paired cvt_pk).
typedef __bf16 bf16;
typedef __attribute__((ext_vector_type(8))) __bf16 bf16x8;
typedef __attribute__((ext_vector_type(4))) __bf16 bf16x4;
typedef __attribute__((ext_vector_type(4))) float f32x4;

#define NQ     512
#define NC     131072
#define DIM    192
#define HID    256
#define NY     10
#define NSLICE 512           // cand slices of 256; k_dist grid = 2*NSLICE

#define KL2E   2.0813689810056077f    // (log2 e)^2
#define N2KL2E -4.1627379620112154f   // -2*(log2 e)^2

// ---------------- workspace layout (bytes) ----------------
#define OFF_W1B 0u                              // 24 planes x 256 x 8 B fp8 = 49152
#define OFF_W2B (OFF_W1B + 49152u)              // 32 planes x 192 x 8 B fp8 = 49152
#define OFF_XE8 (OFF_W2B + 49152u)              // 24 planes x 512 x 8 B fp8 = 98304
#define OFF_X2  (OFF_XE8 + 98304u)              // 512 f32 = 2048
#define OFF_CE8 (OFF_X2 + 2048u)                // 131072x192 fp8 = 25165824
#define OFF_C2  (OFF_CE8 + 25165824u)           // 131072 f32 = 524288
#define OFF_ACC (OFF_C2 + 524288u)              // 8 x 512 x 16 f32 = 262144
#define OFF_YB  (OFF_ACC + 262144u)             // 4194304

static __device__ __forceinline__ unsigned pk4(float a, float b, float c, float d) {
  unsigned w = __builtin_amdgcn_cvt_pk_fp8_f32(a, b, 0, false);
  w = __builtin_amdgcn_cvt_pk_fp8_f32(c, d, w, true);
  return w;
}

// ---------------- K0: fp8 weight planes + Y B-frag pack + ACC zero ------
__global__ __launch_bounds__(256) void k_prep(const float* __restrict__ W1,
                                              const float* __restrict__ W2,
                                              const float* __restrict__ cy,
                                              unsigned char* __restrict__ W1B8,
                                              unsigned char* __restrict__ W2B8,
                                              bf16* __restrict__ YB,
                                              float* __restrict__ ACC) {
  if (blockIdx.x < 384) {
    int idx = blockIdx.x * 256 + threadIdx.x;   // 0..98303
    if (idx < 192 * 256) {
      int k = idx / 256, n = idx % 256;
      int p = (k >> 5) * 4 + ((k >> 3) & 3);
      int pk = __builtin_amdgcn_cvt_pk_fp8_f32(W1[idx], W1[idx], 0, false);
      W1B8[((size_t)(p * 256 + n)) * 8 + (k & 7)] = (unsigned char)(pk & 0xff);
    } else {
      int i2 = idx - 192 * 256;
      int k = i2 / 192, n = i2 % 192;
      int p = (k >> 5) * 4 + ((k >> 3) & 3);
      int pk = __builtin_amdgcn_cvt_pk_fp8_f32(W2[i2], W2[i2], 0, false);
      W2B8[((size_t)(p * 192 + n)) * 8 + (k & 7)] = (unsigned char)(pk & 0xff);
    }
  } else if (blockIdx.x < 1408) {
    int u = (blockIdx.x - 384) * 256 + threadIdx.x;   // 0..262143
    int p32 = u >> 6, lane6 = u & 63;
    int qq = lane6 >> 4, l15 = lane6 & 15;
    bf16x8 v;
#pragma unroll
    for (int jj = 0; jj < 8; jj++) {
      int cand = p32 * 32 + qq * 8 + jj;
      float x = (l15 < 10) ? cy[(size_t)cand * NY + l15] : (l15 == 10 ? 1.f : 0.f);
      v[jj] = (bf16)x;
    }
    *(bf16x8*)&YB[(size_t)u * 8] = v;
  } else {
    // zero ACC: 64 blocks x 256 thr x 16 B = 262144 B (ws is poisoned)
    int idx = (blockIdx.x - 1408) * 256 + threadIdx.x;
    f32x4 z = {0.f, 0.f, 0.f, 0.f};
    *(f32x4*)&ACC[idx * 4] = z;
  }
}

// ---------------- K1: fp8 encode + residual MLP (merged q+c, 256 thr) ----
// 3 barriers: encode -> G1(full H) -> G2+epilogue(in-place zt8) -> copyout.
// zt8 stride 208 (2-way b64 alias = free), hth8 stride 264 (conflict-free).
// GEMMs computed TRANSPOSED (A=weights, B=z): lane holds 4 consecutive
// output columns at row (tile*16 + l15) -> dword LDS epilogues.
__global__ __launch_bounds__(256, 4) void k_encode(
    const float* __restrict__ xnq, const int* __restrict__ xcq,
    const float* __restrict__ xnc, const int* __restrict__ xcc,
    const float* __restrict__ Wn, const float* __restrict__ bn,
    const float* __restrict__ emb, const float* __restrict__ b1,
    const float* __restrict__ b2, const unsigned char* __restrict__ W1B8,
    const unsigned char* __restrict__ W2B8, unsigned char* __restrict__ ce8,
    unsigned char* __restrict__ xe8, float* __restrict__ x2v,
    float* __restrict__ c2v) {
  __shared__ alignas(16) unsigned char zt8[64][208];    // fp8 z / output (13.3 KB)
  __shared__ alignas(16) unsigned char hth8[64][264];   // fp8 hidden, full 256 (16.9 KB)
  __shared__ float n2l[64];

  const int t = threadIdx.x;
  const bool isq = blockIdx.x < 8;
  const int row0 = (isq ? blockIdx.x : blockIdx.x - 8) * 64;
  const float* __restrict__ xn = isq ? xnq : xnc;
  const int* __restrict__ xc = isq ? xcq : xcc;
  const int lane = t & 63, w = t >> 6;       // wave 0..3
  const int l15 = lane & 15, q = lane >> 4;

  if (t < 64) n2l[t] = 0.f;

  // ---- encode: wave w -> num features {2w,2w+1} + cat feature w (fp8) ----
  {
    const int g = row0 + lane;
    float2 xv2 = *(const float2*)&xn[(size_t)g * 8 + 2 * w];
    int cv = xc[g * 4 + w];
#pragma unroll
    for (int f01 = 0; f01 < 2; f01++) {
      int f = 2 * w + f01;
      float xv = f01 ? xv2.y : xv2.x;
      float zz[16];
#pragma unroll
      for (int i = 0; i < 4; i++) {
        f32x4 wv = *(const f32x4*)&Wn[f * 16 + i * 4];
        f32x4 bv = *(const f32x4*)&bn[f * 16 + i * 4];
#pragma unroll
        for (int u = 0; u < 4; u++) zz[i * 4 + u] = xv * wv[u] + bv[u];
      }
      uint4 pk;
      pk.x = pk4(zz[0], zz[1], zz[2], zz[3]);
      pk.y = pk4(zz[4], zz[5], zz[6], zz[7]);
      pk.z = pk4(zz[8], zz[9], zz[10], zz[11]);
      pk.w = pk4(zz[12], zz[13], zz[14], zz[15]);
      *(uint4*)&zt8[lane][f * 16] = pk;
    }
    const float* er = &emb[(size_t)(w * 100 + cv) * 16];
    f32x4 e0 = *(const f32x4*)&er[0];
    f32x4 e1 = *(const f32x4*)&er[4];
    f32x4 e2 = *(const f32x4*)&er[8];
    f32x4 e3 = *(const f32x4*)&er[12];
    uint4 pk;
    pk.x = pk4(e0[0], e0[1], e0[2], e0[3]);
    pk.y = pk4(e1[0], e1[1], e1[2], e1[3]);
    pk.z = pk4(e2[0], e2[1], e2[2], e2[3]);
    pk.w = pk4(e3[0], e3[1], e3[2], e3[3]);
    *(uint4*)&zt8[lane][128 + w * 16] = pk;
  }
  __syncthreads();

  f32x4 z4 = {0.f, 0.f, 0.f, 0.f};

  // ---- G1 (fp8, transposed): H = relu(Z @ W1 + b1); wave w owns cols
  // [64w, 64w+64). acc1[mi][ni][r] = H[mi*16+l15][64w+16ni+4q+r].
  {
    f32x4 acc1[4][4];          // [mi][ni]
#pragma unroll
    for (int mi = 0; mi < 4; mi++)
#pragma unroll
      for (int ni = 0; ni < 4; ni++) acc1[mi][ni] = z4;
#pragma unroll 2
    for (int kk = 0; kk < 192; kk += 32) {
      long a[4], b[4];
#pragma unroll
      for (int mi = 0; mi < 4; mi++)
        a[mi] = *(const long*)&zt8[mi * 16 + l15][kk + q * 8];
      const unsigned char* wp = &W1B8[(size_t)(((kk >> 5) * 4 + q) * 256 + w * 64 + l15) * 8];
#pragma unroll
      for (int ni = 0; ni < 4; ni++)
        b[ni] = *(const long*)&wp[ni * 128];
#pragma unroll
      for (int mi = 0; mi < 4; mi++)
#pragma unroll
        for (int ni = 0; ni < 4; ni++)
          acc1[mi][ni] = __builtin_amdgcn_mfma_f32_16x16x32_fp8_fp8(b[ni], a[mi], acc1[mi][ni], 0, 0, 0);
    }
#pragma unroll
    for (int ni = 0; ni < 4; ni++) {
      f32x4 bb = *(const f32x4*)&b1[w * 64 + ni * 16 + q * 4];
#pragma unroll
      for (int mi = 0; mi < 4; mi++) {
        float h0 = acc1[mi][ni][0] + bb[0]; h0 = h0 > 0.f ? h0 : 0.f;
        float h1 = acc1[mi][ni][1] + bb[1]; h1 = h1 > 0.f ? h1 : 0.f;
        float h2 = acc1[mi][ni][2] + bb[2]; h2 = h2 > 0.f ? h2 : 0.f;
        float h3 = acc1[mi][ni][3] + bb[3]; h3 = h3 > 0.f ? h3 : 0.f;
        *(unsigned*)&hth8[mi * 16 + l15][w * 64 + ni * 16 + q * 4] = pk4(h0, h1, h2, h3);
      }
    }
  }
  __syncthreads();

  // ---- G2 (fp8, transposed): acc2 = H @ W2; wave w owns cols [48w, 48w+48)
  // acc2[mi][ni][r] = (H@W2)[mi*16+l15][48w+16ni+4q+r].
  f32x4 acc2[4][3];
#pragma unroll
  for (int mi = 0; mi < 4; mi++)
#pragma unroll
    for (int ni = 0; ni < 3; ni++) acc2[mi][ni] = z4;
#pragma unroll 2
  for (int kk = 0; kk < 256; kk += 32) {
    long a[4], b[3];
#pragma unroll
    for (int mi = 0; mi < 4; mi++)
      a[mi] = *(const long*)&hth8[mi * 16 + l15][kk + q * 8];
    const unsigned char* wp = &W2B8[(size_t)(((kk >> 5) * 4 + q) * 192 + w * 48 + l15) * 8];
#pragma unroll
    for (int ni = 0; ni < 3; ni++)
      b[ni] = *(const long*)&wp[ni * 128];
#pragma unroll
    for (int mi = 0; mi < 4; mi++)
#pragma unroll
      for (int ni = 0; ni < 3; ni++)
        acc2[mi][ni] = __builtin_amdgcn_mfma_f32_16x16x32_fp8_fp8(b[ni], a[mi], acc2[mi][ni], 0, 0, 0);
  }

  // ---- epilogue: v = z + acc2 + b2 -> fp8 in-place in zt8 (dword ops),
  // norms of the ROUNDED values accumulated per row, pre-scaled by KL2E ----
  // Safe: all zt8 G1 B-frag reads completed at the post-G1 barrier.
  {
    float nrm[4];              // per mi: row rr = mi*16 + l15
#pragma unroll
    for (int mi = 0; mi < 4; mi++) nrm[mi] = 0.f;
#pragma unroll
    for (int ni = 0; ni < 3; ni++) {
      const int n0 = w * 48 + ni * 16 + q * 4;
      f32x4 bb = *(const f32x4*)&b2[n0];
#pragma unroll
      for (int mi = 0; mi < 4; mi++) {
        const int rr = mi * 16 + l15;
        unsigned old = *(const unsigned*)&zt8[rr][n0];
        float v0 = __builtin_amdgcn_cvt_f32_fp8((int)old, 0) + acc2[mi][ni][0] + bb[0];
        float v1 = __builtin_amdgcn_cvt_f32_fp8((int)old, 1) + acc2[mi][ni][1] + bb[1];
        float v2 = __builtin_amdgcn_cvt_f32_fp8((int)old, 2) + acc2[mi][ni][2] + bb[2];
        float v3 = __builtin_amdgcn_cvt_f32_fp8((int)old, 3) + acc2[mi][ni][3] + bb[3];
        unsigned pkw = pk4(v0, v1, v2, v3);
        *(unsigned*)&zt8[rr][n0] = pkw;
        float r0 = __builtin_amdgcn_cvt_f32_fp8((int)pkw, 0);
        float r1 = __builtin_amdgcn_cvt_f32_fp8((int)pkw, 1);
        float r2 = __builtin_amdgcn_cvt_f32_fp8((int)pkw, 2);
        float r3 = __builtin_amdgcn_cvt_f32_fp8((int)pkw, 3);
        nrm[mi] += r0 * r0 + r1 * r1 + r2 * r2 + r3 * r3;
      }
    }
#pragma unroll
    for (int mi = 0; mi < 4; mi++) {
      float s = nrm[mi];
      s += __shfl_xor(s, 16);
      s += __shfl_xor(s, 32);
      if (lane < 16) atomicAdd(&n2l[mi * 16 + l15], s);
    }
  }
  __syncthreads();

  // ---- copy-out (fp8) ----
  if (isq) {
    // queries: B-plane layout xe8[(p*512 + row)*8 + j]
    for (int cc = w; cc < 24; cc += 4) {
      long v = *(const long*)&zt8[lane][cc * 8];
      *(long*)&xe8[((size_t)cc * NQ + row0 + lane) * 8] = v;
    }
    if (t < 64) x2v[row0 + t] = n2l[t] * KL2E;
  } else {
    // candidates: row-major 192 B rows, coalesced uint copies
    unsigned int* dst = (unsigned int*)(ce8 + (size_t)row0 * DIM);
#pragma unroll
    for (int i = 0; i < 12; i++) {
      int j = t + 256 * i;                   // 0..3071 words
      int r = j / 48, cb = (j - r * 48) * 4;
      dst[j] = *(const unsigned int*)&zt8[r][cb];
    }
    if (t < 64) c2v[row0 + t] = n2l[t] * KL2E;
  }
}

// ---------------- K3: fp8 dist + exp2 + bf16 PV ------------------------
// v16: double-buffered ct8 staging (issue-early; vmcnt wait after compute).
// v19: XCD-chunked slice remap. v20: nq-split acc[4][2] x2, 112 regs.
// v22: epilogue = LDS stage (unchanged) -> barrier -> thread t does 11
// atomicAdds for query qh+t into XCD-local ACC[i8] (i8=blockIdx&7 is
// XCD-constant under the remap). Uniform base + t*64 + i*4: ~3 VGPRs,
// after the acc live range. No P buffer, no k_comb.
__global__ __launch_bounds__(256, 4) void k_dist(
    const unsigned char* __restrict__ xe8, const float* __restrict__ x2v,
    const unsigned char* __restrict__ ce8, const float* __restrict__ c2v,
    const bf16* __restrict__ YB, float* __restrict__ ACC) {
  __shared__ alignas(16) unsigned char ct8[2][64][208]; // 26.6 KB dbuf
  __shared__ alignas(16) bf16 ET[4][16][72];            // per-wave exp tiles (9.2 KB)

  const int t = threadIdx.x;
  const int raw = blockIdx.x;
  const int half = raw >> 9;
  const int r9 = raw & (NSLICE - 1);
  const int slice = (r9 & 7) * 64 + (r9 >> 3);  // XCD-chunked, bijective
  const int n0 = slice * 256;
  const int qh = half * 256;
  const int lane = t & 63, w = t >> 6;
  const int l15 = lane & 15, q = lane >> 4;
  const int qbase = qh + w * 64;               // wave's 64 queries, fixed
  const int sr = t >> 2, squ = t & 3;          // staging: 48 B per thread

  f32x4 z4 = {0.f, 0.f, 0.f, 0.f};
  f32x4 oacc[4];               // [nq global] — compile-time indexed only
#pragma unroll
  for (int nq = 0; nq < 4; nq++) oacc[nq] = z4;

  // query norms (pre-scaled by KL2E) hoisted once
  float x2a[4];
#pragma unroll
  for (int nq = 0; nq < 4; nq++) x2a[nq] = x2v[qbase + nq * 16 + l15];

  // ---- initial stage: tile 0 -> ct8[0] ----
  {
    const uint4* src = (const uint4*)(ce8 + (size_t)(n0 + sr) * DIM + squ * 48);
    uint4* dst = (uint4*)&ct8[0][sr][squ * 48];
#pragma unroll
    for (int i = 0; i < 3; i++) dst[i] = src[i];
  }

#pragma unroll 1
  for (int c = 0; c < 4; ++c) {
    const int cb = c & 1;
    // issue-early: tile c+1 global loads fly during barrier + compute
    uint4 pf0, pf1, pf2;
    if (c < 3) {
      const uint4* src = (const uint4*)(ce8 + (size_t)(n0 + (c + 1) * 64 + sr) * DIM + squ * 48);
      pf0 = src[0]; pf1 = src[1]; pf2 = src[2];
    }
    __syncthreads();                           // ct8[cb] writes visible

    // Y B-frags: pre-packed bf16, lane-contiguous
    bf16x8 yf[2];
#pragma unroll
    for (int kb = 0; kb < 2; kb++)
      yf[kb] = *(const bf16x8*)&YB[((size_t)((slice * 8) + c * 2 + kb) * 64 + lane) * 8];
    // candidate norms (pre-scaled): broadcast f32x4 loads
    f32x4 c2r[4];
#pragma unroll
    for (int mc = 0; mc < 4; mc++)
      c2r[mc] = *(const f32x4*)&c2v[n0 + c * 64 + mc * 16 + q * 4];

    // two query-half passes: acc[4][2] each (32 AGPR, reused)
#pragma unroll
    for (int nqh = 0; nqh < 2; nqh++) {
      f32x4 acc[4][2];         // [mc][j], global nq = nqh*2 + j
#pragma unroll
      for (int mc = 0; mc < 4; mc++)
#pragma unroll
        for (int j = 0; j < 2; j++) acc[mc][j] = z4;

#pragma unroll 2
      for (int kk = 0; kk < 192; kk += 32) {
        long a[4], b[2];
#pragma unroll
        for (int mc = 0; mc < 4; mc++)
          a[mc] = *(const long*)&ct8[cb][mc * 16 + l15][kk + q * 8];
        const unsigned char* xp = &xe8[(size_t)(((kk >> 5) * 4 + q) * NQ + qbase + nqh * 32 + l15) * 8];
#pragma unroll
        for (int j = 0; j < 2; j++)
          b[j] = *(const long*)&xp[j * 128];
#pragma unroll
        for (int mc = 0; mc < 4; mc++)
#pragma unroll
          for (int j = 0; j < 2; j++)
            acc[mc][j] = __builtin_amdgcn_mfma_f32_16x16x32_fp8_fp8(a[mc], b[j], acc[mc][j], 0, 0, 0);
      }

      // epilogue: e = exp2(-sqrt(|K*d2|)); ET -> PV MFMA, per global nq
#pragma unroll
      for (int j = 0; j < 2; ++j) {
        const int nq = nqh * 2 + j;
#pragma unroll
        for (int mc = 0; mc < 4; mc++) {
          bf16x4 ev;
#pragma unroll
          for (int r = 0; r < 4; r++) {
            float d2 = __builtin_fmaf(N2KL2E, acc[mc][j][r], x2a[nq] + c2r[mc][r]);
            ev[r] = (bf16)__builtin_amdgcn_exp2f(-__builtin_amdgcn_sqrtf(__builtin_fabsf(d2)));
          }
          *(bf16x4*)&ET[w][l15][mc * 16 + q * 4] = ev;
        }
#pragma unroll
        for (int kb = 0; kb < 2; kb++) {
          bf16x8 a = *(const bf16x8*)&ET[w][l15][kb * 32 + q * 8];
          oacc[nq] = __builtin_amdgcn_mfma_f32_16x16x32_bf16(a, yf[kb], oacc[nq], 0, 0, 0);
        }
      }
    }

    // write prefetched tile c+1 into the other buffer (vmcnt wait here,
    // after compute — latency hidden). Safe: readers of that buffer
    // finished before this iteration's top barrier.
    if (c < 3) {
      uint4* dst = (uint4*)&ct8[cb ^ 1][sr][squ * 48];
      dst[0] = pf0; dst[1] = pf1; dst[2] = pf2;
    }
  }

  // ---- stage in LDS (ct8 dead), then XCD-local atomic accumulate ----
  __syncthreads();
  float* Pst = (float*)&ct8[0][0][0];          // 256 q x 12 = 12.3 KB
  if (l15 < 11) {
#pragma unroll
    for (int nq = 0; nq < 4; nq++)
#pragma unroll
      for (int r = 0; r < 4; r++) {
        int lq = w * 64 + nq * 16 + q * 4 + r;
        Pst[lq * 12 + l15] = oacc[nq][r];
      }
  }
  __syncthreads();
  {
    // thread t owns query qh+t: 11 atomics, addresses base + i*4
    const int i8 = raw & 7;                    // XCD-constant under remap
    float* ab = ACC + ((size_t)i8 * NQ + qh + t) * 16;
#pragma unroll
    for (int i = 0; i < 11; i++)
      atomicAdd(ab + i, Pst[t * 12 + i]);
  }
}

// ---------------- K4: normalize (sum 8 sub-accumulators, divide) --------
__global__ __launch_bounds__(256) void k_norm(const float* __restrict__ ACC,
                                              float* __restrict__ out) {
  int u = blockIdx.x * 256 + threadIdx.x;      // 32 blocks -> 8192 threads
  int qy = u >> 4, y = u & 15;
  if (y < 10) {
    float o = 0.f, l = 0.f;
#pragma unroll
    for (int i = 0; i < 8; i++) {
      o += ACC[((size_t)i * NQ + qy) * 16 + y];
      l += ACC[((size_t)i * NQ + qy) * 16 + 10];
    }
    out[qy * NY + y] = o / l;
  }
}

// ---------------- launcher ----------------
extern "C" void kernel_launch(void* const* d_in, const int* in_sizes, int n_in,
                              void* d_out, int out_size, void* d_ws, size_t ws_size,
                              hipStream_t stream) {
  (void)in_sizes; (void)n_in; (void)out_size; (void)ws_size;
  const float* x_num = (const float*)d_in[0];
  const int*   x_cat = (const int*)d_in[1];
  const float* c_num = (const float*)d_in[2];
  const int*   c_cat = (const int*)d_in[3];
  const float* c_y   = (const float*)d_in[4];
  const float* W_num = (const float*)d_in[5];
  const float* b_num = (const float*)d_in[6];
  const float* emb   = (const float*)d_in[7];
  const float* W1    = (const float*)d_in[8];
  const float* b1    = (const float*)d_in[9];
  const float* W2    = (const float*)d_in[10];
  const float* b2    = (const float*)d_in[11];
  float* out = (float*)d_out;

  char* ws = (char*)d_ws;
  unsigned char* W1B8 = (unsigned char*)(ws + OFF_W1B);
  unsigned char* W2B8 = (unsigned char*)(ws + OFF_W2B);
  unsigned char* xe8  = (unsigned char*)(ws + OFF_XE8);
  float* x2v = (float*)(ws + OFF_X2);
  unsigned char* ce8  = (unsigned char*)(ws + OFF_CE8);
  float* c2v = (float*)(ws + OFF_C2);
  float* ACC = (float*)(ws + OFF_ACC);
  bf16*  YB  = (bf16*)(ws + OFF_YB);

  k_prep<<<dim3(1472), dim3(256), 0, stream>>>(W1, W2, c_y, W1B8, W2B8, YB, ACC);
  k_encode<<<dim3(8 + NC / 64), dim3(256), 0, stream>>>(
      x_num, x_cat, c_num, c_cat, W_num, b_num, emb, b1, b2, W1B8, W2B8,
      ce8, xe8, x2v, c2v);
  k_dist<<<dim3(2 * NSLICE), dim3(256), 0, stream>>>(xe8, x2v, ce8, c2v, YB, ACC);
  k_norm<<<dim3(32), dim3(256), 0, stream>>>(ACC, out);
}

// Round 11
// 156.350 us; speedup vs baseline: 2.3868x; 2.3868x over previous
//
#include <hip/hip_runtime.h>
#include <hip/hip_bf16.h>

// ModernNCA fused pipeline, v23.
// B=512 queries, N=131072 candidates, D=192, H=256, NY=10.
// v23: v20 base + k_dist accumulator split moved from nq-axis to MC-axis
// while KEEPING ct8 LDS staging. Three atomic-ACC attempts (v17 cliff,
// v18 spill, v22 atomic-RMW 91MB WRITE / 256us) prove the P round-trip is
// structurally cheaper -- P-buffer design is final. v20's nq-split doubled
// LDS a-frag reads (conflicts 2.0M->5.1M); mc-split (proven correct in
// v21) duplicates the L1-resident xe8 b-frags instead. Each pass maps to
// one yf half (kb=mch) -> ET shrinks to [4][16][40] (LDS 35.8->31.7KB).
// yf/c2r loads in pass epilogue (out of GEMM live range). Same 32-AGPR
// acc, 112 regs, (256,4), 4 blocks/CU single round.
// v20: <=128-reg k_dist. v19: transposed P + XCD-chunked slice remap.
// v16: ct8 dbuf issue-early staging. v14: transposed-operand epilogues.
typedef __bf16 bf16;
typedef __attribute__((ext_vector_type(8))) __bf16 bf16x8;
typedef __attribute__((ext_vector_type(4))) __bf16 bf16x4;
typedef __attribute__((ext_vector_type(4))) float f32x4;

#define NQ     512
#define NC     131072
#define DIM    192
#define HID    256
#define NY     10
#define NSLICE 512           // cand slices of 256; k_dist grid = 2*NSLICE

#define KL2E   2.0813689810056077f    // (log2 e)^2
#define N2KL2E -4.1627379620112154f   // -2*(log2 e)^2

// ---------------- workspace layout (bytes) ----------------
#define OFF_W1B 0u                              // 24 planes x 256 x 8 B fp8 = 49152
#define OFF_W2B (OFF_W1B + 49152u)              // 32 planes x 192 x 8 B fp8 = 49152
#define OFF_XE8 (OFF_W2B + 49152u)              // 24 planes x 512 x 8 B fp8 = 98304
#define OFF_X2  (OFF_XE8 + 98304u)              // 512 f32 = 2048
#define OFF_CE8 (OFF_X2 + 2048u)                // 131072x192 fp8 = 25165824
#define OFF_C2  (OFF_CE8 + 25165824u)           // 131072 f32 = 524288
#define OFF_P   (OFF_C2 + 524288u)              // 512 qy x 512 slice x 12 f32 = 12582912
#define OFF_YB  (OFF_P + 12582912u)             // 4194304

static __device__ __forceinline__ unsigned pk4(float a, float b, float c, float d) {
  unsigned w = __builtin_amdgcn_cvt_pk_fp8_f32(a, b, 0, false);
  w = __builtin_amdgcn_cvt_pk_fp8_f32(c, d, w, true);
  return w;
}

// ---------------- K0: fp8 weight planes + Y B-fragment pack ----------
__global__ __launch_bounds__(256) void k_prep(const float* __restrict__ W1,
                                              const float* __restrict__ W2,
                                              const float* __restrict__ cy,
                                              unsigned char* __restrict__ W1B8,
                                              unsigned char* __restrict__ W2B8,
                                              bf16* __restrict__ YB) {
  if (blockIdx.x < 384) {
    int idx = blockIdx.x * 256 + threadIdx.x;   // 0..98303
    if (idx < 192 * 256) {
      int k = idx / 256, n = idx % 256;
      int p = (k >> 5) * 4 + ((k >> 3) & 3);
      int pk = __builtin_amdgcn_cvt_pk_fp8_f32(W1[idx], W1[idx], 0, false);
      W1B8[((size_t)(p * 256 + n)) * 8 + (k & 7)] = (unsigned char)(pk & 0xff);
    } else {
      int i2 = idx - 192 * 256;
      int k = i2 / 192, n = i2 % 192;
      int p = (k >> 5) * 4 + ((k >> 3) & 3);
      int pk = __builtin_amdgcn_cvt_pk_fp8_f32(W2[i2], W2[i2], 0, false);
      W2B8[((size_t)(p * 192 + n)) * 8 + (k & 7)] = (unsigned char)(pk & 0xff);
    }
  } else {
    int u = (blockIdx.x - 384) * 256 + threadIdx.x;   // 0..262143
    int p32 = u >> 6, lane6 = u & 63;
    int qq = lane6 >> 4, l15 = lane6 & 15;
    bf16x8 v;
#pragma unroll
    for (int jj = 0; jj < 8; jj++) {
      int cand = p32 * 32 + qq * 8 + jj;
      float x = (l15 < 10) ? cy[(size_t)cand * NY + l15] : (l15 == 10 ? 1.f : 0.f);
      v[jj] = (bf16)x;
    }
    *(bf16x8*)&YB[(size_t)u * 8] = v;
  }
}

// ---------------- K1: fp8 encode + residual MLP (merged q+c, 256 thr) ----
// 3 barriers: encode -> G1(full H) -> G2+epilogue(in-place zt8) -> copyout.
// zt8 stride 208 (2-way b64 alias = free), hth8 stride 264 (conflict-free).
// GEMMs computed TRANSPOSED (A=weights, B=z): lane holds 4 consecutive
// output columns at row (tile*16 + l15) -> dword LDS epilogues.
__global__ __launch_bounds__(256, 4) void k_encode(
    const float* __restrict__ xnq, const int* __restrict__ xcq,
    const float* __restrict__ xnc, const int* __restrict__ xcc,
    const float* __restrict__ Wn, const float* __restrict__ bn,
    const float* __restrict__ emb, const float* __restrict__ b1,
    const float* __restrict__ b2, const unsigned char* __restrict__ W1B8,
    const unsigned char* __restrict__ W2B8, unsigned char* __restrict__ ce8,
    unsigned char* __restrict__ xe8, float* __restrict__ x2v,
    float* __restrict__ c2v) {
  __shared__ alignas(16) unsigned char zt8[64][208];    // fp8 z / output (13.3 KB)
  __shared__ alignas(16) unsigned char hth8[64][264];   // fp8 hidden, full 256 (16.9 KB)
  __shared__ float n2l[64];

  const int t = threadIdx.x;
  const bool isq = blockIdx.x < 8;
  const int row0 = (isq ? blockIdx.x : blockIdx.x - 8) * 64;
  const float* __restrict__ xn = isq ? xnq : xnc;
  const int* __restrict__ xc = isq ? xcq : xcc;
  const int lane = t & 63, w = t >> 6;       // wave 0..3
  const int l15 = lane & 15, q = lane >> 4;

  if (t < 64) n2l[t] = 0.f;

  // ---- encode: wave w -> num features {2w,2w+1} + cat feature w (fp8) ----
  {
    const int g = row0 + lane;
    float2 xv2 = *(const float2*)&xn[(size_t)g * 8 + 2 * w];
    int cv = xc[g * 4 + w];
#pragma unroll
    for (int f01 = 0; f01 < 2; f01++) {
      int f = 2 * w + f01;
      float xv = f01 ? xv2.y : xv2.x;
      float zz[16];
#pragma unroll
      for (int i = 0; i < 4; i++) {
        f32x4 wv = *(const f32x4*)&Wn[f * 16 + i * 4];
        f32x4 bv = *(const f32x4*)&bn[f * 16 + i * 4];
#pragma unroll
        for (int u = 0; u < 4; u++) zz[i * 4 + u] = xv * wv[u] + bv[u];
      }
      uint4 pk;
      pk.x = pk4(zz[0], zz[1], zz[2], zz[3]);
      pk.y = pk4(zz[4], zz[5], zz[6], zz[7]);
      pk.z = pk4(zz[8], zz[9], zz[10], zz[11]);
      pk.w = pk4(zz[12], zz[13], zz[14], zz[15]);
      *(uint4*)&zt8[lane][f * 16] = pk;
    }
    const float* er = &emb[(size_t)(w * 100 + cv) * 16];
    f32x4 e0 = *(const f32x4*)&er[0];
    f32x4 e1 = *(const f32x4*)&er[4];
    f32x4 e2 = *(const f32x4*)&er[8];
    f32x4 e3 = *(const f32x4*)&er[12];
    uint4 pk;
    pk.x = pk4(e0[0], e0[1], e0[2], e0[3]);
    pk.y = pk4(e1[0], e1[1], e1[2], e1[3]);
    pk.z = pk4(e2[0], e2[1], e2[2], e2[3]);
    pk.w = pk4(e3[0], e3[1], e3[2], e3[3]);
    *(uint4*)&zt8[lane][128 + w * 16] = pk;
  }
  __syncthreads();

  f32x4 z4 = {0.f, 0.f, 0.f, 0.f};

  // ---- G1 (fp8, transposed): H = relu(Z @ W1 + b1); wave w owns cols
  // [64w, 64w+64). acc1[mi][ni][r] = H[mi*16+l15][64w+16ni+4q+r].
  {
    f32x4 acc1[4][4];          // [mi][ni]
#pragma unroll
    for (int mi = 0; mi < 4; mi++)
#pragma unroll
      for (int ni = 0; ni < 4; ni++) acc1[mi][ni] = z4;
#pragma unroll 2
    for (int kk = 0; kk < 192; kk += 32) {
      long a[4], b[4];
#pragma unroll
      for (int mi = 0; mi < 4; mi++)
        a[mi] = *(const long*)&zt8[mi * 16 + l15][kk + q * 8];
      const unsigned char* wp = &W1B8[(size_t)(((kk >> 5) * 4 + q) * 256 + w * 64 + l15) * 8];
#pragma unroll
      for (int ni = 0; ni < 4; ni++)
        b[ni] = *(const long*)&wp[ni * 128];
#pragma unroll
      for (int mi = 0; mi < 4; mi++)
#pragma unroll
        for (int ni = 0; ni < 4; ni++)
          acc1[mi][ni] = __builtin_amdgcn_mfma_f32_16x16x32_fp8_fp8(b[ni], a[mi], acc1[mi][ni], 0, 0, 0);
    }
#pragma unroll
    for (int ni = 0; ni < 4; ni++) {
      f32x4 bb = *(const f32x4*)&b1[w * 64 + ni * 16 + q * 4];
#pragma unroll
      for (int mi = 0; mi < 4; mi++) {
        float h0 = acc1[mi][ni][0] + bb[0]; h0 = h0 > 0.f ? h0 : 0.f;
        float h1 = acc1[mi][ni][1] + bb[1]; h1 = h1 > 0.f ? h1 : 0.f;
        float h2 = acc1[mi][ni][2] + bb[2]; h2 = h2 > 0.f ? h2 : 0.f;
        float h3 = acc1[mi][ni][3] + bb[3]; h3 = h3 > 0.f ? h3 : 0.f;
        *(unsigned*)&hth8[mi * 16 + l15][w * 64 + ni * 16 + q * 4] = pk4(h0, h1, h2, h3);
      }
    }
  }
  __syncthreads();

  // ---- G2 (fp8, transposed): acc2 = H @ W2; wave w owns cols [48w, 48w+48)
  // acc2[mi][ni][r] = (H@W2)[mi*16+l15][48w+16ni+4q+r].
  f32x4 acc2[4][3];
#pragma unroll
  for (int mi = 0; mi < 4; mi++)
#pragma unroll
    for (int ni = 0; ni < 3; ni++) acc2[mi][ni] = z4;
#pragma unroll 2
  for (int kk = 0; kk < 256; kk += 32) {
    long a[4], b[3];
#pragma unroll
    for (int mi = 0; mi < 4; mi++)
      a[mi] = *(const long*)&hth8[mi * 16 + l15][kk + q * 8];
    const unsigned char* wp = &W2B8[(size_t)(((kk >> 5) * 4 + q) * 192 + w * 48 + l15) * 8];
#pragma unroll
    for (int ni = 0; ni < 3; ni++)
      b[ni] = *(const long*)&wp[ni * 128];
#pragma unroll
    for (int mi = 0; mi < 4; mi++)
#pragma unroll
      for (int ni = 0; ni < 3; ni++)
        acc2[mi][ni] = __builtin_amdgcn_mfma_f32_16x16x32_fp8_fp8(b[ni], a[mi], acc2[mi][ni], 0, 0, 0);
  }

  // ---- epilogue: v = z + acc2 + b2 -> fp8 in-place in zt8 (dword ops),
  // norms of the ROUNDED values accumulated per row, pre-scaled by KL2E ----
  // Safe: all zt8 G1 B-frag reads completed at the post-G1 barrier.
  {
    float nrm[4];              // per mi: row rr = mi*16 + l15
#pragma unroll
    for (int mi = 0; mi < 4; mi++) nrm[mi] = 0.f;
#pragma unroll
    for (int ni = 0; ni < 3; ni++) {
      const int n0 = w * 48 + ni * 16 + q * 4;
      f32x4 bb = *(const f32x4*)&b2[n0];
#pragma unroll
      for (int mi = 0; mi < 4; mi++) {
        const int rr = mi * 16 + l15;
        unsigned old = *(const unsigned*)&zt8[rr][n0];
        float v0 = __builtin_amdgcn_cvt_f32_fp8((int)old, 0) + acc2[mi][ni][0] + bb[0];
        float v1 = __builtin_amdgcn_cvt_f32_fp8((int)old, 1) + acc2[mi][ni][1] + bb[1];
        float v2 = __builtin_amdgcn_cvt_f32_fp8((int)old, 2) + acc2[mi][ni][2] + bb[2];
        float v3 = __builtin_amdgcn_cvt_f32_fp8((int)old, 3) + acc2[mi][ni][3] + bb[3];
        unsigned pkw = pk4(v0, v1, v2, v3);
        *(unsigned*)&zt8[rr][n0] = pkw;
        float r0 = __builtin_amdgcn_cvt_f32_fp8((int)pkw, 0);
        float r1 = __builtin_amdgcn_cvt_f32_fp8((int)pkw, 1);
        float r2 = __builtin_amdgcn_cvt_f32_fp8((int)pkw, 2);
        float r3 = __builtin_amdgcn_cvt_f32_fp8((int)pkw, 3);
        nrm[mi] += r0 * r0 + r1 * r1 + r2 * r2 + r3 * r3;
      }
    }
#pragma unroll
    for (int mi = 0; mi < 4; mi++) {
      float s = nrm[mi];
      s += __shfl_xor(s, 16);
      s += __shfl_xor(s, 32);
      if (lane < 16) atomicAdd(&n2l[mi * 16 + l15], s);
    }
  }
  __syncthreads();

  // ---- copy-out (fp8) ----
  if (isq) {
    // queries: B-plane layout xe8[(p*512 + row)*8 + j]
    for (int cc = w; cc < 24; cc += 4) {
      long v = *(const long*)&zt8[lane][cc * 8];
      *(long*)&xe8[((size_t)cc * NQ + row0 + lane) * 8] = v;
    }
    if (t < 64) x2v[row0 + t] = n2l[t] * KL2E;
  } else {
    // candidates: row-major 192 B rows, coalesced uint copies
    unsigned int* dst = (unsigned int*)(ce8 + (size_t)row0 * DIM);
#pragma unroll
    for (int i = 0; i < 12; i++) {
      int j = t + 256 * i;                   // 0..3071 words
      int r = j / 48, cb = (j - r * 48) * 4;
      dst[j] = *(const unsigned int*)&zt8[r][cb];
    }
    if (t < 64) c2v[row0 + t] = n2l[t] * KL2E;
  }
}

// ---------------- K3: fp8 dist + exp2 + bf16 PV ------------------------
// v16: double-buffered ct8 staging (issue-early; vmcnt wait after compute).
// v19: XCD-chunked slice remap + transposed P records.
// v23: MC-split accumulator -- per c-tile, two passes of acc[2][4] over
// cand halves (mch = kb). a-frags from LDS once per pass (24 b64/c-iter,
// back to v16 count); duplicated loads are the L1-resident xe8 b-frags.
// ET per pass is 32 cands -> [4][16][40] (5 KB). 112 regs, (256,4).
__global__ __launch_bounds__(256, 4) void k_dist(
    const unsigned char* __restrict__ xe8, const float* __restrict__ x2v,
    const unsigned char* __restrict__ ce8, const float* __restrict__ c2v,
    const bf16* __restrict__ YB, float* __restrict__ P) {
  __shared__ alignas(16) unsigned char ct8[2][64][208]; // 26.6 KB dbuf
  __shared__ alignas(16) bf16 ET[4][16][40];            // 5 KB per-wave exp tiles

  const int t = threadIdx.x;
  const int raw = blockIdx.x;
  const int half = raw >> 9;
  const int r9 = raw & (NSLICE - 1);
  const int slice = (r9 & 7) * 64 + (r9 >> 3);  // XCD-chunked, bijective
  const int n0 = slice * 256;
  const int qh = half * 256;
  const int lane = t & 63, w = t >> 6;
  const int l15 = lane & 15, q = lane >> 4;
  const int qbase = qh + w * 64;               // wave's 64 queries, fixed
  const int sr = t >> 2, squ = t & 3;          // staging: 48 B per thread

  f32x4 z4 = {0.f, 0.f, 0.f, 0.f};
  f32x4 oacc[4];               // [nq] — compile-time indexed only
#pragma unroll
  for (int nq = 0; nq < 4; nq++) oacc[nq] = z4;

  // query norms (pre-scaled by KL2E) hoisted once
  float x2a[4];
#pragma unroll
  for (int nq = 0; nq < 4; nq++) x2a[nq] = x2v[qbase + nq * 16 + l15];

  // ---- initial stage: tile 0 -> ct8[0] ----
  {
    const uint4* src = (const uint4*)(ce8 + (size_t)(n0 + sr) * DIM + squ * 48);
    uint4* dst = (uint4*)&ct8[0][sr][squ * 48];
#pragma unroll
    for (int i = 0; i < 3; i++) dst[i] = src[i];
  }

#pragma unroll 1
  for (int c = 0; c < 4; ++c) {
    const int cb = c & 1;
    // issue-early: tile c+1 global loads fly during barrier + compute
    uint4 pf0, pf1, pf2;
    if (c < 3) {
      const uint4* src = (const uint4*)(ce8 + (size_t)(n0 + (c + 1) * 64 + sr) * DIM + squ * 48);
      pf0 = src[0]; pf1 = src[1]; pf2 = src[2];
    }
    __syncthreads();                           // ct8[cb] writes visible

    // two candidate-half passes: acc[2][4] (32 AGPR, reused); mch == kb
#pragma unroll
    for (int mch = 0; mch < 2; mch++) {
      f32x4 acc[2][4];         // [mc2][nq]; global mc = mch*2 + mc2
#pragma unroll
      for (int mc2 = 0; mc2 < 2; mc2++)
#pragma unroll
        for (int nq = 0; nq < 4; nq++) acc[mc2][nq] = z4;

#pragma unroll 2
      for (int kk = 0; kk < 192; kk += 32) {
        long a[2], b[4];
#pragma unroll
        for (int mc2 = 0; mc2 < 2; mc2++)
          a[mc2] = *(const long*)&ct8[cb][(mch * 2 + mc2) * 16 + l15][kk + q * 8];
        const unsigned char* xp = &xe8[(size_t)(((kk >> 5) * 4 + q) * NQ + qbase + l15) * 8];
#pragma unroll
        for (int nq = 0; nq < 4; nq++)
          b[nq] = *(const long*)&xp[nq * 128];
#pragma unroll
        for (int mc2 = 0; mc2 < 2; mc2++)
#pragma unroll
          for (int nq = 0; nq < 4; nq++)
            acc[mc2][nq] = __builtin_amdgcn_mfma_f32_16x16x32_fp8_fp8(a[mc2], b[nq], acc[mc2][nq], 0, 0, 0);
      }

      // epilogue operands for this 32-cand group (loaded post-GEMM)
      bf16x8 yf = *(const bf16x8*)&YB[((size_t)(slice * 8 + c * 2 + mch) * 64 + lane) * 8];
      f32x4 c2p[2];
#pragma unroll
      for (int mc2 = 0; mc2 < 2; mc2++)
        c2p[mc2] = *(const f32x4*)&c2v[n0 + c * 64 + mch * 32 + mc2 * 16 + q * 4];

      // e = exp2(-sqrt(|K*d2|)); ET transpose (per-wave) -> PV MFMA
#pragma unroll
      for (int nq = 0; nq < 4; ++nq) {
#pragma unroll
        for (int mc2 = 0; mc2 < 2; mc2++) {
          bf16x4 ev;
#pragma unroll
          for (int r = 0; r < 4; r++) {
            float d2 = __builtin_fmaf(N2KL2E, acc[mc2][nq][r], x2a[nq] + c2p[mc2][r]);
            ev[r] = (bf16)__builtin_amdgcn_exp2f(-__builtin_amdgcn_sqrtf(__builtin_fabsf(d2)));
          }
          *(bf16x4*)&ET[w][l15][mc2 * 16 + q * 4] = ev;
        }
        bf16x8 a = *(const bf16x8*)&ET[w][l15][q * 8];
        oacc[nq] = __builtin_amdgcn_mfma_f32_16x16x32_bf16(a, yf, oacc[nq], 0, 0, 0);
      }
    }

    // write prefetched tile c+1 into the other buffer (vmcnt wait here,
    // after compute — latency hidden). Safe: readers of that buffer
    // finished before this iteration's top barrier.
    if (c < 3) {
      uint4* dst = (uint4*)&ct8[cb ^ 1][sr][squ * 48];
      dst[0] = pf0; dst[1] = pf1; dst[2] = pf2;
    }
  }

  // ---- P write: stage in LDS (ct8 dead), then transposed records ----
  __syncthreads();
  float* Pst = (float*)&ct8[0][0][0];          // 256 q x 12 = 12.3 KB
  if (l15 < 11) {
#pragma unroll
    for (int nq = 0; nq < 4; nq++)
#pragma unroll
      for (int r = 0; r < 4; r++) {
        int lq = w * 64 + nq * 16 + q * 4 + r;
        Pst[lq * 12 + l15] = oacc[nq][r];
      }
  }
  __syncthreads();
  {
    const f32x4* Ps = (const f32x4*)Pst;
    float* Pb = P + ((size_t)qh * NSLICE + slice) * 12;
#pragma unroll
    for (int i = t; i < 768; i += 256) {
      int lq = i / 3, part = i % 3;            // record (qh+lq, slice)
      *(f32x4*)&Pb[(size_t)lq * NSLICE * 12 + part * 4] = Ps[i];
    }
  }
}

// ---------------- K4: combine (contiguous per-query P run) --------------
__global__ __launch_bounds__(512) void k_comb(const float* __restrict__ P,
                                              float* __restrict__ out) {
  __shared__ float red[8][11];
  const int t = threadIdx.x;
  const int qy = blockIdx.x;
  const int lane = t & 63, w = t >> 6;

  // record (qy, slice=t): contiguous 24 KB run per block
  const float* p = &P[((size_t)qy * NSLICE + t) * 12];
  f32x4 v0 = *(const f32x4*)&p[0];
  f32x4 v1 = *(const f32x4*)&p[4];
  f32x4 v2 = *(const f32x4*)&p[8];
  float s[11];
#pragma unroll
  for (int j = 0; j < 4; j++) s[j] = v0[j];
#pragma unroll
  for (int j = 0; j < 4; j++) s[4 + j] = v1[j];
#pragma unroll
  for (int j = 0; j < 3; j++) s[8 + j] = v2[j];
#pragma unroll
  for (int d = 1; d < 64; d <<= 1)
#pragma unroll
    for (int j = 0; j < 11; j++) s[j] += __shfl_xor(s[j], d);
  if (lane == 0)
#pragma unroll
    for (int j = 0; j < 11; j++) red[w][j] = s[j];
  __syncthreads();
  if (t < 10) {
    float o = 0.f, l = 0.f;
#pragma unroll
    for (int i = 0; i < 8; i++) { o += red[i][t]; l += red[i][10]; }
    out[qy * NY + t] = o / l;
  }
}

// ---------------- launcher ----------------
extern "C" void kernel_launch(void* const* d_in, const int* in_sizes, int n_in,
                              void* d_out, int out_size, void* d_ws, size_t ws_size,
                              hipStream_t stream) {
  (void)in_sizes; (void)n_in; (void)out_size; (void)ws_size;
  const float* x_num = (const float*)d_in[0];
  const int*   x_cat = (const int*)d_in[1];
  const float* c_num = (const float*)d_in[2];
  const int*   c_cat = (const int*)d_in[3];
  const float* c_y   = (const float*)d_in[4];
  const float* W_num = (const float*)d_in[5];
  const float* b_num = (const float*)d_in[6];
  const float* emb   = (const float*)d_in[7];
  const float* W1    = (const float*)d_in[8];
  const float* b1    = (const float*)d_in[9];
  const float* W2    = (const float*)d_in[10];
  const float* b2    = (const float*)d_in[11];
  float* out = (float*)d_out;

  char* ws = (char*)d_ws;
  unsigned char* W1B8 = (unsigned char*)(ws + OFF_W1B);
  unsigned char* W2B8 = (unsigned char*)(ws + OFF_W2B);
  unsigned char* xe8  = (unsigned char*)(ws + OFF_XE8);
  float* x2v = (float*)(ws + OFF_X2);
  unsigned char* ce8  = (unsigned char*)(ws + OFF_CE8);
  float* c2v = (float*)(ws + OFF_C2);
  float* P   = (float*)(ws + OFF_P);
  bf16*  YB  = (bf16*)(ws + OFF_YB);

  k_prep<<<dim3(1408), dim3(256), 0, stream>>>(W1, W2, c_y, W1B8, W2B8, YB);
  k_encode<<<dim3(8 + NC / 64), dim3(256), 0, stream>>>(
      x_num, x_cat, c_num, c_cat, W_num, b_num, emb, b1, b2, W1B8, W2B8,
      ce8, xe8, x2v, c2v);
  k_dist<<<dim3(2 * NSLICE), dim3(256), 0, stream>>>(xe8, x2v, ce8, c2v, YB, P);
  k_comb<<<dim3(NQ), dim3(512), 0, stream>>>(P, out);
}

// Round 12
// 154.086 us; speedup vs baseline: 2.4218x; 1.0147x over previous
//
#include <hip/hip_runtime.h>
#include <hip/hip_bf16.h>

// ModernNCA fused pipeline, v24 == v20 (verbatim revert; best measured
// 153.3us). Search summary for posterity:
//  - v21 (global-operand k_dist, no LDS staging): REFUTED, FETCH 15->55MB,
//    WRITE 13->58MB, k_dist 61us. LDS staging + block lockstep is load-
//    bearing.
//  - v22 (atomic ACC epilogue): REFUTED, 64B-stride atomics -> partial-line
//    RMW, WRITE 91MB, k_dist 256us. With v17 (addr-hoist cliff) and v18
//    (forced-cap spill) this closes the line: P round-trip < any atomic
//    accumulate on this grid.
//  - v23 (mc-split acc): REFUTED, 156.3 vs 153.3 -- duplicated global
//    b-loads cost >= saved LDS conflicts (5.1M conflict cycles are mostly
//    HIDDEN under MFMA; counter != exposed cycles). nq-split is final.
// Timed region includes a ~44-48us harness workspace re-poison fill
// (268MB @ ~70% HBM peak) -- immovable floor.
// v20: k_dist nq-split acc[4][2] x2 passes, 112 regs, (256,4), exact
// 4-blocks/CU single dispatch round.
// v19: transposed P [qy][slice] + XCD-chunked slice remap; contig k_comb.
// v16: ct8 double-buffer w/ issue-early staging (vmcnt after compute).
// v14: transposed-operand MFMA epilogues (dword LDS, paired cvt_pk).
typedef __bf16 bf16;
typedef __attribute__((ext_vector_type(8))) __bf16 bf16x8;
typedef __attribute__((ext_vector_type(4))) __bf16 bf16x4;
typedef __attribute__((ext_vector_type(4))) float f32x4;

#define NQ     512
#define NC     131072
#define DIM    192
#define HID    256
#define NY     10
#define NSLICE 512           // cand slices of 256; k_dist grid = 2*NSLICE

#define KL2E   2.0813689810056077f    // (log2 e)^2
#define N2KL2E -4.1627379620112154f   // -2*(log2 e)^2

// ---------------- workspace layout (bytes) ----------------
#define OFF_W1B 0u                              // 24 planes x 256 x 8 B fp8 = 49152
#define OFF_W2B (OFF_W1B + 49152u)              // 32 planes x 192 x 8 B fp8 = 49152
#define OFF_XE8 (OFF_W2B + 49152u)              // 24 planes x 512 x 8 B fp8 = 98304
#define OFF_X2  (OFF_XE8 + 98304u)              // 512 f32 = 2048
#define OFF_CE8 (OFF_X2 + 2048u)                // 131072x192 fp8 = 25165824
#define OFF_C2  (OFF_CE8 + 25165824u)           // 131072 f32 = 524288
#define OFF_P   (OFF_C2 + 524288u)              // 512 qy x 512 slice x 12 f32 = 12582912
#define OFF_YB  (OFF_P + 12582912u)             // 4194304

static __device__ __forceinline__ unsigned pk4(float a, float b, float c, float d) {
  unsigned w = __builtin_amdgcn_cvt_pk_fp8_f32(a, b, 0, false);
  w = __builtin_amdgcn_cvt_pk_fp8_f32(c, d, w, true);
  return w;
}

// ---------------- K0: fp8 weight planes + Y B-fragment pack ----------
__global__ __launch_bounds__(256) void k_prep(const float* __restrict__ W1,
                                              const float* __restrict__ W2,
                                              const float* __restrict__ cy,
                                              unsigned char* __restrict__ W1B8,
                                              unsigned char* __restrict__ W2B8,
                                              bf16* __restrict__ YB) {
  if (blockIdx.x < 384) {
    int idx = blockIdx.x * 256 + threadIdx.x;   // 0..98303
    if (idx < 192 * 256) {
      int k = idx / 256, n = idx % 256;
      int p = (k >> 5) * 4 + ((k >> 3) & 3);
      int pk = __builtin_amdgcn_cvt_pk_fp8_f32(W1[idx], W1[idx], 0, false);
      W1B8[((size_t)(p * 256 + n)) * 8 + (k & 7)] = (unsigned char)(pk & 0xff);
    } else {
      int i2 = idx - 192 * 256;
      int k = i2 / 192, n = i2 % 192;
      int p = (k >> 5) * 4 + ((k >> 3) & 3);
      int pk = __builtin_amdgcn_cvt_pk_fp8_f32(W2[i2], W2[i2], 0, false);
      W2B8[((size_t)(p * 192 + n)) * 8 + (k & 7)] = (unsigned char)(pk & 0xff);
    }
  } else {
    int u = (blockIdx.x - 384) * 256 + threadIdx.x;   // 0..262143
    int p32 = u >> 6, lane6 = u & 63;
    int qq = lane6 >> 4, l15 = lane6 & 15;
    bf16x8 v;
#pragma unroll
    for (int jj = 0; jj < 8; jj++) {
      int cand = p32 * 32 + qq * 8 + jj;
      float x = (l15 < 10) ? cy[(size_t)cand * NY + l15] : (l15 == 10 ? 1.f : 0.f);
      v[jj] = (bf16)x;
    }
    *(bf16x8*)&YB[(size_t)u * 8] = v;
  }
}

// ---------------- K1: fp8 encode + residual MLP (merged q+c, 256 thr) ----
// 3 barriers: encode -> G1(full H) -> G2+epilogue(in-place zt8) -> copyout.
// zt8 stride 208 (2-way b64 alias = free), hth8 stride 264 (conflict-free).
// GEMMs computed TRANSPOSED (A=weights, B=z): lane holds 4 consecutive
// output columns at row (tile*16 + l15) -> dword LDS epilogues.
__global__ __launch_bounds__(256, 4) void k_encode(
    const float* __restrict__ xnq, const int* __restrict__ xcq,
    const float* __restrict__ xnc, const int* __restrict__ xcc,
    const float* __restrict__ Wn, const float* __restrict__ bn,
    const float* __restrict__ emb, const float* __restrict__ b1,
    const float* __restrict__ b2, const unsigned char* __restrict__ W1B8,
    const unsigned char* __restrict__ W2B8, unsigned char* __restrict__ ce8,
    unsigned char* __restrict__ xe8, float* __restrict__ x2v,
    float* __restrict__ c2v) {
  __shared__ alignas(16) unsigned char zt8[64][208];    // fp8 z / output (13.3 KB)
  __shared__ alignas(16) unsigned char hth8[64][264];   // fp8 hidden, full 256 (16.9 KB)
  __shared__ float n2l[64];

  const int t = threadIdx.x;
  const bool isq = blockIdx.x < 8;
  const int row0 = (isq ? blockIdx.x : blockIdx.x - 8) * 64;
  const float* __restrict__ xn = isq ? xnq : xnc;
  const int* __restrict__ xc = isq ? xcq : xcc;
  const int lane = t & 63, w = t >> 6;       // wave 0..3
  const int l15 = lane & 15, q = lane >> 4;

  if (t < 64) n2l[t] = 0.f;

  // ---- encode: wave w -> num features {2w,2w+1} + cat feature w (fp8) ----
  {
    const int g = row0 + lane;
    float2 xv2 = *(const float2*)&xn[(size_t)g * 8 + 2 * w];
    int cv = xc[g * 4 + w];
#pragma unroll
    for (int f01 = 0; f01 < 2; f01++) {
      int f = 2 * w + f01;
      float xv = f01 ? xv2.y : xv2.x;
      float zz[16];
#pragma unroll
      for (int i = 0; i < 4; i++) {
        f32x4 wv = *(const f32x4*)&Wn[f * 16 + i * 4];
        f32x4 bv = *(const f32x4*)&bn[f * 16 + i * 4];
#pragma unroll
        for (int u = 0; u < 4; u++) zz[i * 4 + u] = xv * wv[u] + bv[u];
      }
      uint4 pk;
      pk.x = pk4(zz[0], zz[1], zz[2], zz[3]);
      pk.y = pk4(zz[4], zz[5], zz[6], zz[7]);
      pk.z = pk4(zz[8], zz[9], zz[10], zz[11]);
      pk.w = pk4(zz[12], zz[13], zz[14], zz[15]);
      *(uint4*)&zt8[lane][f * 16] = pk;
    }
    const float* er = &emb[(size_t)(w * 100 + cv) * 16];
    f32x4 e0 = *(const f32x4*)&er[0];
    f32x4 e1 = *(const f32x4*)&er[4];
    f32x4 e2 = *(const f32x4*)&er[8];
    f32x4 e3 = *(const f32x4*)&er[12];
    uint4 pk;
    pk.x = pk4(e0[0], e0[1], e0[2], e0[3]);
    pk.y = pk4(e1[0], e1[1], e1[2], e1[3]);
    pk.z = pk4(e2[0], e2[1], e2[2], e2[3]);
    pk.w = pk4(e3[0], e3[1], e3[2], e3[3]);
    *(uint4*)&zt8[lane][128 + w * 16] = pk;
  }
  __syncthreads();

  f32x4 z4 = {0.f, 0.f, 0.f, 0.f};

  // ---- G1 (fp8, transposed): H = relu(Z @ W1 + b1); wave w owns cols
  // [64w, 64w+64). acc1[mi][ni][r] = H[mi*16+l15][64w+16ni+4q+r].
  {
    f32x4 acc1[4][4];          // [mi][ni]
#pragma unroll
    for (int mi = 0; mi < 4; mi++)
#pragma unroll
      for (int ni = 0; ni < 4; ni++) acc1[mi][ni] = z4;
#pragma unroll 2
    for (int kk = 0; kk < 192; kk += 32) {
      long a[4], b[4];
#pragma unroll
      for (int mi = 0; mi < 4; mi++)
        a[mi] = *(const long*)&zt8[mi * 16 + l15][kk + q * 8];
      const unsigned char* wp = &W1B8[(size_t)(((kk >> 5) * 4 + q) * 256 + w * 64 + l15) * 8];
#pragma unroll
      for (int ni = 0; ni < 4; ni++)
        b[ni] = *(const long*)&wp[ni * 128];
#pragma unroll
      for (int mi = 0; mi < 4; mi++)
#pragma unroll
        for (int ni = 0; ni < 4; ni++)
          acc1[mi][ni] = __builtin_amdgcn_mfma_f32_16x16x32_fp8_fp8(b[ni], a[mi], acc1[mi][ni], 0, 0, 0);
    }
#pragma unroll
    for (int ni = 0; ni < 4; ni++) {
      f32x4 bb = *(const f32x4*)&b1[w * 64 + ni * 16 + q * 4];
#pragma unroll
      for (int mi = 0; mi < 4; mi++) {
        float h0 = acc1[mi][ni][0] + bb[0]; h0 = h0 > 0.f ? h0 : 0.f;
        float h1 = acc1[mi][ni][1] + bb[1]; h1 = h1 > 0.f ? h1 : 0.f;
        float h2 = acc1[mi][ni][2] + bb[2]; h2 = h2 > 0.f ? h2 : 0.f;
        float h3 = acc1[mi][ni][3] + bb[3]; h3 = h3 > 0.f ? h3 : 0.f;
        *(unsigned*)&hth8[mi * 16 + l15][w * 64 + ni * 16 + q * 4] = pk4(h0, h1, h2, h3);
      }
    }
  }
  __syncthreads();

  // ---- G2 (fp8, transposed): acc2 = H @ W2; wave w owns cols [48w, 48w+48)
  // acc2[mi][ni][r] = (H@W2)[mi*16+l15][48w+16ni+4q+r].
  f32x4 acc2[4][3];
#pragma unroll
  for (int mi = 0; mi < 4; mi++)
#pragma unroll
    for (int ni = 0; ni < 3; ni++) acc2[mi][ni] = z4;
#pragma unroll 2
  for (int kk = 0; kk < 256; kk += 32) {
    long a[4], b[3];
#pragma unroll
    for (int mi = 0; mi < 4; mi++)
      a[mi] = *(const long*)&hth8[mi * 16 + l15][kk + q * 8];
    const unsigned char* wp = &W2B8[(size_t)(((kk >> 5) * 4 + q) * 192 + w * 48 + l15) * 8];
#pragma unroll
    for (int ni = 0; ni < 3; ni++)
      b[ni] = *(const long*)&wp[ni * 128];
#pragma unroll
    for (int mi = 0; mi < 4; mi++)
#pragma unroll
      for (int ni = 0; ni < 3; ni++)
        acc2[mi][ni] = __builtin_amdgcn_mfma_f32_16x16x32_fp8_fp8(b[ni], a[mi], acc2[mi][ni], 0, 0, 0);
  }

  // ---- epilogue: v = z + acc2 + b2 -> fp8 in-place in zt8 (dword ops),
  // norms of the ROUNDED values accumulated per row, pre-scaled by KL2E ----
  // Safe: all zt8 G1 B-frag reads completed at the post-G1 barrier.
  {
    float nrm[4];              // per mi: row rr = mi*16 + l15
#pragma unroll
    for (int mi = 0; mi < 4; mi++) nrm[mi] = 0.f;
#pragma unroll
    for (int ni = 0; ni < 3; ni++) {
      const int n0 = w * 48 + ni * 16 + q * 4;
      f32x4 bb = *(const f32x4*)&b2[n0];
#pragma unroll
      for (int mi = 0; mi < 4; mi++) {
        const int rr = mi * 16 + l15;
        unsigned old = *(const unsigned*)&zt8[rr][n0];
        float v0 = __builtin_amdgcn_cvt_f32_fp8((int)old, 0) + acc2[mi][ni][0] + bb[0];
        float v1 = __builtin_amdgcn_cvt_f32_fp8((int)old, 1) + acc2[mi][ni][1] + bb[1];
        float v2 = __builtin_amdgcn_cvt_f32_fp8((int)old, 2) + acc2[mi][ni][2] + bb[2];
        float v3 = __builtin_amdgcn_cvt_f32_fp8((int)old, 3) + acc2[mi][ni][3] + bb[3];
        unsigned pkw = pk4(v0, v1, v2, v3);
        *(unsigned*)&zt8[rr][n0] = pkw;
        float r0 = __builtin_amdgcn_cvt_f32_fp8((int)pkw, 0);
        float r1 = __builtin_amdgcn_cvt_f32_fp8((int)pkw, 1);
        float r2 = __builtin_amdgcn_cvt_f32_fp8((int)pkw, 2);
        float r3 = __builtin_amdgcn_cvt_f32_fp8((int)pkw, 3);
        nrm[mi] += r0 * r0 + r1 * r1 + r2 * r2 + r3 * r3;
      }
    }
#pragma unroll
    for (int mi = 0; mi < 4; mi++) {
      float s = nrm[mi];
      s += __shfl_xor(s, 16);
      s += __shfl_xor(s, 32);
      if (lane < 16) atomicAdd(&n2l[mi * 16 + l15], s);
    }
  }
  __syncthreads();

  // ---- copy-out (fp8) ----
  if (isq) {
    // queries: B-plane layout xe8[(p*512 + row)*8 + j]
    for (int cc = w; cc < 24; cc += 4) {
      long v = *(const long*)&zt8[lane][cc * 8];
      *(long*)&xe8[((size_t)cc * NQ + row0 + lane) * 8] = v;
    }
    if (t < 64) x2v[row0 + t] = n2l[t] * KL2E;
  } else {
    // candidates: row-major 192 B rows, coalesced uint copies
    unsigned int* dst = (unsigned int*)(ce8 + (size_t)row0 * DIM);
#pragma unroll
    for (int i = 0; i < 12; i++) {
      int j = t + 256 * i;                   // 0..3071 words
      int r = j / 48, cb = (j - r * 48) * 4;
      dst[j] = *(const unsigned int*)&zt8[r][cb];
    }
    if (t < 64) c2v[row0 + t] = n2l[t] * KL2E;
  }
}

// ---------------- K3: fp8 dist + exp2 + bf16 PV ------------------------
// v16: double-buffered ct8 staging (issue-early; vmcnt wait after compute).
// v19: XCD-chunked slice remap + transposed P records.
// v20: query-axis accumulator split -- per c-tile, two passes of acc[4][2]
// (nqh = 0,1). AGPR 80 -> 48 (acc 32 + oacc 16); total ~112 <= 128 ->
// launch_bounds(256,4), 4 blocks/CU, single dispatch round. Global xe8
// b-loads per c-iter unchanged (24); ds a-frag reads double (cheap --
// v23 measured the conflict cycles as hidden under MFMA).
__global__ __launch_bounds__(256, 4) void k_dist(
    const unsigned char* __restrict__ xe8, const float* __restrict__ x2v,
    const unsigned char* __restrict__ ce8, const float* __restrict__ c2v,
    const bf16* __restrict__ YB, float* __restrict__ P) {
  __shared__ alignas(16) unsigned char ct8[2][64][208]; // 26.6 KB dbuf
  __shared__ alignas(16) bf16 ET[4][16][72];            // per-wave exp tiles (9.2 KB)

  const int t = threadIdx.x;
  const int raw = blockIdx.x;
  const int half = raw >> 9;
  const int r9 = raw & (NSLICE - 1);
  const int slice = (r9 & 7) * 64 + (r9 >> 3);  // XCD-chunked, bijective
  const int n0 = slice * 256;
  const int qh = half * 256;
  const int lane = t & 63, w = t >> 6;
  const int l15 = lane & 15, q = lane >> 4;
  const int qbase = qh + w * 64;               // wave's 64 queries, fixed
  const int sr = t >> 2, squ = t & 3;          // staging: 48 B per thread

  f32x4 z4 = {0.f, 0.f, 0.f, 0.f};
  f32x4 oacc[4];               // [nq global] — compile-time indexed only
#pragma unroll
  for (int nq = 0; nq < 4; nq++) oacc[nq] = z4;

  // query norms (pre-scaled by KL2E) hoisted once
  float x2a[4];
#pragma unroll
  for (int nq = 0; nq < 4; nq++) x2a[nq] = x2v[qbase + nq * 16 + l15];

  // ---- initial stage: tile 0 -> ct8[0] ----
  {
    const uint4* src = (const uint4*)(ce8 + (size_t)(n0 + sr) * DIM + squ * 48);
    uint4* dst = (uint4*)&ct8[0][sr][squ * 48];
#pragma unroll
    for (int i = 0; i < 3; i++) dst[i] = src[i];
  }

#pragma unroll 1
  for (int c = 0; c < 4; ++c) {
    const int cb = c & 1;
    // issue-early: tile c+1 global loads fly during barrier + compute
    uint4 pf0, pf1, pf2;
    if (c < 3) {
      const uint4* src = (const uint4*)(ce8 + (size_t)(n0 + (c + 1) * 64 + sr) * DIM + squ * 48);
      pf0 = src[0]; pf1 = src[1]; pf2 = src[2];
    }
    __syncthreads();                           // ct8[cb] writes visible

    // Y B-frags: pre-packed bf16, lane-contiguous
    bf16x8 yf[2];
#pragma unroll
    for (int kb = 0; kb < 2; kb++)
      yf[kb] = *(const bf16x8*)&YB[((size_t)((slice * 8) + c * 2 + kb) * 64 + lane) * 8];
    // candidate norms (pre-scaled): broadcast f32x4 loads
    f32x4 c2r[4];
#pragma unroll
    for (int mc = 0; mc < 4; mc++)
      c2r[mc] = *(const f32x4*)&c2v[n0 + c * 64 + mc * 16 + q * 4];

    // two query-half passes: acc[4][2] each (32 AGPR, reused)
#pragma unroll
    for (int nqh = 0; nqh < 2; nqh++) {
      f32x4 acc[4][2];         // [mc][j], global nq = nqh*2 + j
#pragma unroll
      for (int mc = 0; mc < 4; mc++)
#pragma unroll
        for (int j = 0; j < 2; j++) acc[mc][j] = z4;

#pragma unroll 2
      for (int kk = 0; kk < 192; kk += 32) {
        long a[4], b[2];
#pragma unroll
        for (int mc = 0; mc < 4; mc++)
          a[mc] = *(const long*)&ct8[cb][mc * 16 + l15][kk + q * 8];
        const unsigned char* xp = &xe8[(size_t)(((kk >> 5) * 4 + q) * NQ + qbase + nqh * 32 + l15) * 8];
#pragma unroll
        for (int j = 0; j < 2; j++)
          b[j] = *(const long*)&xp[j * 128];
#pragma unroll
        for (int mc = 0; mc < 4; mc++)
#pragma unroll
          for (int j = 0; j < 2; j++)
            acc[mc][j] = __builtin_amdgcn_mfma_f32_16x16x32_fp8_fp8(a[mc], b[j], acc[mc][j], 0, 0, 0);
      }

      // epilogue: e = exp2(-sqrt(|K*d2|)); ET -> PV MFMA, per global nq
#pragma unroll
      for (int j = 0; j < 2; ++j) {
        const int nq = nqh * 2 + j;
#pragma unroll
        for (int mc = 0; mc < 4; mc++) {
          bf16x4 ev;
#pragma unroll
          for (int r = 0; r < 4; r++) {
            float d2 = __builtin_fmaf(N2KL2E, acc[mc][j][r], x2a[nq] + c2r[mc][r]);
            ev[r] = (bf16)__builtin_amdgcn_exp2f(-__builtin_amdgcn_sqrtf(__builtin_fabsf(d2)));
          }
          *(bf16x4*)&ET[w][l15][mc * 16 + q * 4] = ev;
        }
#pragma unroll
        for (int kb = 0; kb < 2; kb++) {
          bf16x8 a = *(const bf16x8*)&ET[w][l15][kb * 32 + q * 8];
          oacc[nq] = __builtin_amdgcn_mfma_f32_16x16x32_bf16(a, yf[kb], oacc[nq], 0, 0, 0);
        }
      }
    }

    // write prefetched tile c+1 into the other buffer (vmcnt wait here,
    // after compute — latency hidden). Safe: readers of that buffer
    // finished before this iteration's top barrier.
    if (c < 3) {
      uint4* dst = (uint4*)&ct8[cb ^ 1][sr][squ * 48];
      dst[0] = pf0; dst[1] = pf1; dst[2] = pf2;
    }
  }

  // ---- P write: stage in LDS (ct8 dead), then transposed records ----
  __syncthreads();
  float* Pst = (float*)&ct8[0][0][0];          // 256 q x 12 = 12.3 KB
  if (l15 < 11) {
#pragma unroll
    for (int nq = 0; nq < 4; nq++)
#pragma unroll
      for (int r = 0; r < 4; r++) {
        int lq = w * 64 + nq * 16 + q * 4 + r;
        Pst[lq * 12 + l15] = oacc[nq][r];
      }
  }
  __syncthreads();
  {
    const f32x4* Ps = (const f32x4*)Pst;
    float* Pb = P + ((size_t)qh * NSLICE + slice) * 12;
#pragma unroll
    for (int i = t; i < 768; i += 256) {
      int lq = i / 3, part = i % 3;            // record (qh+lq, slice)
      *(f32x4*)&Pb[(size_t)lq * NSLICE * 12 + part * 4] = Ps[i];
    }
  }
}

// ---------------- K4: combine (contiguous per-query P run) --------------
__global__ __launch_bounds__(512) void k_comb(const float* __restrict__ P,
                                              float* __restrict__ out) {
  __shared__ float red[8][11];
  const int t = threadIdx.x;
  const int qy = blockIdx.x;
  const int lane = t & 63, w = t >> 6;

  // record (qy, slice=t): contiguous 24 KB run per block
  const float* p = &P[((size_t)qy * NSLICE + t) * 12];
  f32x4 v0 = *(const f32x4*)&p[0];
  f32x4 v1 = *(const f32x4*)&p[4];
  f32x4 v2 = *(const f32x4*)&p[8];
  float s[11];
#pragma unroll
  for (int j = 0; j < 4; j++) s[j] = v0[j];
#pragma unroll
  for (int j = 0; j < 4; j++) s[4 + j] = v1[j];
#pragma unroll
  for (int j = 0; j < 3; j++) s[8 + j] = v2[j];
#pragma unroll
  for (int d = 1; d < 64; d <<= 1)
#pragma unroll
    for (int j = 0; j < 11; j++) s[j] += __shfl_xor(s[j], d);
  if (lane == 0)
#pragma unroll
    for (int j = 0; j < 11; j++) red[w][j] = s[j];
  __syncthreads();
  if (t < 10) {
    float o = 0.f, l = 0.f;
#pragma unroll
    for (int i = 0; i < 8; i++) { o += red[i][t]; l += red[i][10]; }
    out[qy * NY + t] = o / l;
  }
}

// ---------------- launcher ----------------
extern "C" void kernel_launch(void* const* d_in, const int* in_sizes, int n_in,
                              void* d_out, int out_size, void* d_ws, size_t ws_size,
                              hipStream_t stream) {
  (void)in_sizes; (void)n_in; (void)out_size; (void)ws_size;
  const float* x_num = (const float*)d_in[0];
  const int*   x_cat = (const int*)d_in[1];
  const float* c_num = (const float*)d_in[2];
  const int*   c_cat = (const int*)d_in[3];
  const float* c_y   = (const float*)d_in[4];
  const float* W_num = (const float*)d_in[5];
  const float* b_num = (const float*)d_in[6];
  const float* emb   = (const float*)d_in[7];
  const float* W1    = (const float*)d_in[8];
  const float* b1    = (const float*)d_in[9];
  const float* W2    = (const float*)d_in[10];
  const float* b2    = (const float*)d_in[11];
  float* out = (float*)d_out;

  char* ws = (char*)d_ws;
  unsigned char* W1B8 = (unsigned char*)(ws + OFF_W1B);
  unsigned char* W2B8 = (unsigned char*)(ws + OFF_W2B);
  unsigned char* xe8  = (unsigned char*)(ws + OFF_XE8);
  float* x2v = (float*)(ws + OFF_X2);
  unsigned char* ce8  = (unsigned char*)(ws + OFF_CE8);
  float* c2v = (float*)(ws + OFF_C2);
  float* P   = (float*)(ws + OFF_P);
  bf16*  YB  = (bf16*)(ws + OFF_YB);

  k_prep<<<dim3(1408), dim3(256), 0, stream>>>(W1, W2, c_y, W1B8, W2B8, YB);
  k_encode<<<dim3(8 + NC / 64), dim3(256), 0, stream>>>(
      x_num, x_cat, c_num, c_cat, W_num, b_num, emb, b1, b2, W1B8, W2B8,
      ce8, xe8, x2v, c2v);
  k_dist<<<dim3(2 * NSLICE), dim3(256), 0, stream>>>(xe8, x2v, ce8, c2v, YB, P);
  k_comb<<<dim3(NQ), dim3(512), 0, stream>>>(P, out);
}

// Round 13
// 152.355 us; speedup vs baseline: 2.4493x; 1.0114x over previous
//
#include <hip/hip_runtime.h>
#include <hip/hip_bf16.h>

// ModernNCA fused pipeline, v25.
// B=512 queries, N=131072 candidates, D=192, H=256, NY=10.
// v25: launch-level consolidation -- YB-pack (1024 blocks, consumer is
// k_dist only) moves from k_prep into k_encode's grid as appended light
// blocks (execute concurrently with encode; early-return branch, no
// LDS/barrier touch). k_prep shrinks 1408->384 blocks (weight planes
// only = the true k_encode dependency). Stream order still guarantees
// W1B8/W2B8 -> k_encode and YB -> k_dist. Kernel-internal levers are
// exhausted: v21/v22/v23 refuted (see below), v20 confirmed twice
// (153.3 / 154.1 us).
//  - v21 (global-operand k_dist): FETCH 15->55MB, 61us. Staging is load-
//    bearing. v22 (atomic ACC): WRITE 91MB RMW, 256us. v23 (mc-split):
//    156.3 -- dup global b-loads >= saved (hidden) LDS conflicts.
// Timed region includes ~48us harness workspace re-poison fill (268MB).
// v20: k_dist nq-split acc[4][2] x2, 112 regs, (256,4), 4 blocks/CU.
// v19: transposed P [qy][slice] + XCD-chunked slice remap; contig k_comb.
// v16: ct8 double-buffer w/ issue-early staging. v14: transposed-operand
// MFMA epilogues (dword LDS, paired cvt_pk).
typedef __bf16 bf16;
typedef __attribute__((ext_vector_type(8))) __bf16 bf16x8;
typedef __attribute__((ext_vector_type(4))) __bf16 bf16x4;
typedef __attribute__((ext_vector_type(4))) float f32x4;

#define NQ     512
#define NC     131072
#define DIM    192
#define HID    256
#define NY     10
#define NSLICE 512           // cand slices of 256; k_dist grid = 2*NSLICE

#define KL2E   2.0813689810056077f    // (log2 e)^2
#define N2KL2E -4.1627379620112154f   // -2*(log2 e)^2

// ---------------- workspace layout (bytes) ----------------
#define OFF_W1B 0u                              // 24 planes x 256 x 8 B fp8 = 49152
#define OFF_W2B (OFF_W1B + 49152u)              // 32 planes x 192 x 8 B fp8 = 49152
#define OFF_XE8 (OFF_W2B + 49152u)              // 24 planes x 512 x 8 B fp8 = 98304
#define OFF_X2  (OFF_XE8 + 98304u)              // 512 f32 = 2048
#define OFF_CE8 (OFF_X2 + 2048u)                // 131072x192 fp8 = 25165824
#define OFF_C2  (OFF_CE8 + 25165824u)           // 131072 f32 = 524288
#define OFF_P   (OFF_C2 + 524288u)              // 512 qy x 512 slice x 12 f32 = 12582912
#define OFF_YB  (OFF_P + 12582912u)             // 4194304

static __device__ __forceinline__ unsigned pk4(float a, float b, float c, float d) {
  unsigned w = __builtin_amdgcn_cvt_pk_fp8_f32(a, b, 0, false);
  w = __builtin_amdgcn_cvt_pk_fp8_f32(c, d, w, true);
  return w;
}

// ---------------- K0: fp8 weight planes only (384 blocks) ---------------
__global__ __launch_bounds__(256) void k_prep(const float* __restrict__ W1,
                                              const float* __restrict__ W2,
                                              unsigned char* __restrict__ W1B8,
                                              unsigned char* __restrict__ W2B8) {
  int idx = blockIdx.x * 256 + threadIdx.x;   // 0..98303
  if (idx < 192 * 256) {
    int k = idx / 256, n = idx % 256;
    int p = (k >> 5) * 4 + ((k >> 3) & 3);
    int pk = __builtin_amdgcn_cvt_pk_fp8_f32(W1[idx], W1[idx], 0, false);
    W1B8[((size_t)(p * 256 + n)) * 8 + (k & 7)] = (unsigned char)(pk & 0xff);
  } else {
    int i2 = idx - 192 * 256;
    int k = i2 / 192, n = i2 % 192;
    int p = (k >> 5) * 4 + ((k >> 3) & 3);
    int pk = __builtin_amdgcn_cvt_pk_fp8_f32(W2[i2], W2[i2], 0, false);
    W2B8[((size_t)(p * 192 + n)) * 8 + (k & 7)] = (unsigned char)(pk & 0xff);
  }
}

// ---------------- K1: fp8 encode + residual MLP + YB pack ---------------
// Blocks [0,8): queries. [8,2056): candidates. [2056,3080): YB B-frag
// pack (early-return branch, no LDS/barriers; consumer is k_dist).
// 3 barriers: encode -> G1(full H) -> G2+epilogue(in-place zt8) -> copyout.
// zt8 stride 208 (2-way b64 alias = free), hth8 stride 264 (conflict-free).
// GEMMs computed TRANSPOSED (A=weights, B=z): lane holds 4 consecutive
// output columns at row (tile*16 + l15) -> dword LDS epilogues.
__global__ __launch_bounds__(256, 4) void k_encode(
    const float* __restrict__ xnq, const int* __restrict__ xcq,
    const float* __restrict__ xnc, const int* __restrict__ xcc,
    const float* __restrict__ Wn, const float* __restrict__ bn,
    const float* __restrict__ emb, const float* __restrict__ b1,
    const float* __restrict__ b2, const unsigned char* __restrict__ W1B8,
    const unsigned char* __restrict__ W2B8, unsigned char* __restrict__ ce8,
    unsigned char* __restrict__ xe8, float* __restrict__ x2v,
    float* __restrict__ c2v, const float* __restrict__ cy,
    bf16* __restrict__ YB) {
  __shared__ alignas(16) unsigned char zt8[64][208];    // fp8 z / output (13.3 KB)
  __shared__ alignas(16) unsigned char hth8[64][264];   // fp8 hidden, full 256 (16.9 KB)
  __shared__ float n2l[64];

  const int t = threadIdx.x;

  // ---- YB-pack blocks (uniform branch; no LDS/barrier use) ----
  if (blockIdx.x >= 2056) {
    int u = (blockIdx.x - 2056) * 256 + t;    // 0..262143
    int p32 = u >> 6, lane6 = u & 63;
    int qq = lane6 >> 4, l15y = lane6 & 15;
    bf16x8 v;
#pragma unroll
    for (int jj = 0; jj < 8; jj++) {
      int cand = p32 * 32 + qq * 8 + jj;
      float x = (l15y < 10) ? cy[(size_t)cand * NY + l15y] : (l15y == 10 ? 1.f : 0.f);
      v[jj] = (bf16)x;
    }
    *(bf16x8*)&YB[(size_t)u * 8] = v;
    return;
  }

  const bool isq = blockIdx.x < 8;
  const int row0 = (isq ? blockIdx.x : blockIdx.x - 8) * 64;
  const float* __restrict__ xn = isq ? xnq : xnc;
  const int* __restrict__ xc = isq ? xcq : xcc;
  const int lane = t & 63, w = t >> 6;       // wave 0..3
  const int l15 = lane & 15, q = lane >> 4;

  if (t < 64) n2l[t] = 0.f;

  // ---- encode: wave w -> num features {2w,2w+1} + cat feature w (fp8) ----
  {
    const int g = row0 + lane;
    float2 xv2 = *(const float2*)&xn[(size_t)g * 8 + 2 * w];
    int cv = xc[g * 4 + w];
#pragma unroll
    for (int f01 = 0; f01 < 2; f01++) {
      int f = 2 * w + f01;
      float xv = f01 ? xv2.y : xv2.x;
      float zz[16];
#pragma unroll
      for (int i = 0; i < 4; i++) {
        f32x4 wv = *(const f32x4*)&Wn[f * 16 + i * 4];
        f32x4 bv = *(const f32x4*)&bn[f * 16 + i * 4];
#pragma unroll
        for (int u = 0; u < 4; u++) zz[i * 4 + u] = xv * wv[u] + bv[u];
      }
      uint4 pk;
      pk.x = pk4(zz[0], zz[1], zz[2], zz[3]);
      pk.y = pk4(zz[4], zz[5], zz[6], zz[7]);
      pk.z = pk4(zz[8], zz[9], zz[10], zz[11]);
      pk.w = pk4(zz[12], zz[13], zz[14], zz[15]);
      *(uint4*)&zt8[lane][f * 16] = pk;
    }
    const float* er = &emb[(size_t)(w * 100 + cv) * 16];
    f32x4 e0 = *(const f32x4*)&er[0];
    f32x4 e1 = *(const f32x4*)&er[4];
    f32x4 e2 = *(const f32x4*)&er[8];
    f32x4 e3 = *(const f32x4*)&er[12];
    uint4 pk;
    pk.x = pk4(e0[0], e0[1], e0[2], e0[3]);
    pk.y = pk4(e1[0], e1[1], e1[2], e1[3]);
    pk.z = pk4(e2[0], e2[1], e2[2], e2[3]);
    pk.w = pk4(e3[0], e3[1], e3[2], e3[3]);
    *(uint4*)&zt8[lane][128 + w * 16] = pk;
  }
  __syncthreads();

  f32x4 z4 = {0.f, 0.f, 0.f, 0.f};

  // ---- G1 (fp8, transposed): H = relu(Z @ W1 + b1); wave w owns cols
  // [64w, 64w+64). acc1[mi][ni][r] = H[mi*16+l15][64w+16ni+4q+r].
  {
    f32x4 acc1[4][4];          // [mi][ni]
#pragma unroll
    for (int mi = 0; mi < 4; mi++)
#pragma unroll
      for (int ni = 0; ni < 4; ni++) acc1[mi][ni] = z4;
#pragma unroll 2
    for (int kk = 0; kk < 192; kk += 32) {
      long a[4], b[4];
#pragma unroll
      for (int mi = 0; mi < 4; mi++)
        a[mi] = *(const long*)&zt8[mi * 16 + l15][kk + q * 8];
      const unsigned char* wp = &W1B8[(size_t)(((kk >> 5) * 4 + q) * 256 + w * 64 + l15) * 8];
#pragma unroll
      for (int ni = 0; ni < 4; ni++)
        b[ni] = *(const long*)&wp[ni * 128];
#pragma unroll
      for (int mi = 0; mi < 4; mi++)
#pragma unroll
        for (int ni = 0; ni < 4; ni++)
          acc1[mi][ni] = __builtin_amdgcn_mfma_f32_16x16x32_fp8_fp8(b[ni], a[mi], acc1[mi][ni], 0, 0, 0);
    }
#pragma unroll
    for (int ni = 0; ni < 4; ni++) {
      f32x4 bb = *(const f32x4*)&b1[w * 64 + ni * 16 + q * 4];
#pragma unroll
      for (int mi = 0; mi < 4; mi++) {
        float h0 = acc1[mi][ni][0] + bb[0]; h0 = h0 > 0.f ? h0 : 0.f;
        float h1 = acc1[mi][ni][1] + bb[1]; h1 = h1 > 0.f ? h1 : 0.f;
        float h2 = acc1[mi][ni][2] + bb[2]; h2 = h2 > 0.f ? h2 : 0.f;
        float h3 = acc1[mi][ni][3] + bb[3]; h3 = h3 > 0.f ? h3 : 0.f;
        *(unsigned*)&hth8[mi * 16 + l15][w * 64 + ni * 16 + q * 4] = pk4(h0, h1, h2, h3);
      }
    }
  }
  __syncthreads();

  // ---- G2 (fp8, transposed): acc2 = H @ W2; wave w owns cols [48w, 48w+48)
  // acc2[mi][ni][r] = (H@W2)[mi*16+l15][48w+16ni+4q+r].
  f32x4 acc2[4][3];
#pragma unroll
  for (int mi = 0; mi < 4; mi++)
#pragma unroll
    for (int ni = 0; ni < 3; ni++) acc2[mi][ni] = z4;
#pragma unroll 2
  for (int kk = 0; kk < 256; kk += 32) {
    long a[4], b[3];
#pragma unroll
    for (int mi = 0; mi < 4; mi++)
      a[mi] = *(const long*)&hth8[mi * 16 + l15][kk + q * 8];
    const unsigned char* wp = &W2B8[(size_t)(((kk >> 5) * 4 + q) * 192 + w * 48 + l15) * 8];
#pragma unroll
    for (int ni = 0; ni < 3; ni++)
      b[ni] = *(const long*)&wp[ni * 128];
#pragma unroll
    for (int mi = 0; mi < 4; mi++)
#pragma unroll
      for (int ni = 0; ni < 3; ni++)
        acc2[mi][ni] = __builtin_amdgcn_mfma_f32_16x16x32_fp8_fp8(b[ni], a[mi], acc2[mi][ni], 0, 0, 0);
  }

  // ---- epilogue: v = z + acc2 + b2 -> fp8 in-place in zt8 (dword ops),
  // norms of the ROUNDED values accumulated per row, pre-scaled by KL2E ----
  // Safe: all zt8 G1 B-frag reads completed at the post-G1 barrier.
  {
    float nrm[4];              // per mi: row rr = mi*16 + l15
#pragma unroll
    for (int mi = 0; mi < 4; mi++) nrm[mi] = 0.f;
#pragma unroll
    for (int ni = 0; ni < 3; ni++) {
      const int n0 = w * 48 + ni * 16 + q * 4;
      f32x4 bb = *(const f32x4*)&b2[n0];
#pragma unroll
      for (int mi = 0; mi < 4; mi++) {
        const int rr = mi * 16 + l15;
        unsigned old = *(const unsigned*)&zt8[rr][n0];
        float v0 = __builtin_amdgcn_cvt_f32_fp8((int)old, 0) + acc2[mi][ni][0] + bb[0];
        float v1 = __builtin_amdgcn_cvt_f32_fp8((int)old, 1) + acc2[mi][ni][1] + bb[1];
        float v2 = __builtin_amdgcn_cvt_f32_fp8((int)old, 2) + acc2[mi][ni][2] + bb[2];
        float v3 = __builtin_amdgcn_cvt_f32_fp8((int)old, 3) + acc2[mi][ni][3] + bb[3];
        unsigned pkw = pk4(v0, v1, v2, v3);
        *(unsigned*)&zt8[rr][n0] = pkw;
        float r0 = __builtin_amdgcn_cvt_f32_fp8((int)pkw, 0);
        float r1 = __builtin_amdgcn_cvt_f32_fp8((int)pkw, 1);
        float r2 = __builtin_amdgcn_cvt_f32_fp8((int)pkw, 2);
        float r3 = __builtin_amdgcn_cvt_f32_fp8((int)pkw, 3);
        nrm[mi] += r0 * r0 + r1 * r1 + r2 * r2 + r3 * r3;
      }
    }
#pragma unroll
    for (int mi = 0; mi < 4; mi++) {
      float s = nrm[mi];
      s += __shfl_xor(s, 16);
      s += __shfl_xor(s, 32);
      if (lane < 16) atomicAdd(&n2l[mi * 16 + l15], s);
    }
  }
  __syncthreads();

  // ---- copy-out (fp8) ----
  if (isq) {
    // queries: B-plane layout xe8[(p*512 + row)*8 + j]
    for (int cc = w; cc < 24; cc += 4) {
      long v = *(const long*)&zt8[lane][cc * 8];
      *(long*)&xe8[((size_t)cc * NQ + row0 + lane) * 8] = v;
    }
    if (t < 64) x2v[row0 + t] = n2l[t] * KL2E;
  } else {
    // candidates: row-major 192 B rows, coalesced uint copies
    unsigned int* dst = (unsigned int*)(ce8 + (size_t)row0 * DIM);
#pragma unroll
    for (int i = 0; i < 12; i++) {
      int j = t + 256 * i;                   // 0..3071 words
      int r = j / 48, cb = (j - r * 48) * 4;
      dst[j] = *(const unsigned int*)&zt8[r][cb];
    }
    if (t < 64) c2v[row0 + t] = n2l[t] * KL2E;
  }
}

// ---------------- K3: fp8 dist + exp2 + bf16 PV ------------------------
// v16: double-buffered ct8 staging (issue-early; vmcnt wait after compute).
// v19: XCD-chunked slice remap + transposed P records.
// v20: query-axis accumulator split -- per c-tile, two passes of acc[4][2]
// (nqh = 0,1). AGPR 80 -> 48 (acc 32 + oacc 16); total ~112 <= 128 ->
// launch_bounds(256,4), 4 blocks/CU, single dispatch round.
__global__ __launch_bounds__(256, 4) void k_dist(
    const unsigned char* __restrict__ xe8, const float* __restrict__ x2v,
    const unsigned char* __restrict__ ce8, const float* __restrict__ c2v,
    const bf16* __restrict__ YB, float* __restrict__ P) {
  __shared__ alignas(16) unsigned char ct8[2][64][208]; // 26.6 KB dbuf
  __shared__ alignas(16) bf16 ET[4][16][72];            // per-wave exp tiles (9.2 KB)

  const int t = threadIdx.x;
  const int raw = blockIdx.x;
  const int half = raw >> 9;
  const int r9 = raw & (NSLICE - 1);
  const int slice = (r9 & 7) * 64 + (r9 >> 3);  // XCD-chunked, bijective
  const int n0 = slice * 256;
  const int qh = half * 256;
  const int lane = t & 63, w = t >> 6;
  const int l15 = lane & 15, q = lane >> 4;
  const int qbase = qh + w * 64;               // wave's 64 queries, fixed
  const int sr = t >> 2, squ = t & 3;          // staging: 48 B per thread

  f32x4 z4 = {0.f, 0.f, 0.f, 0.f};
  f32x4 oacc[4];               // [nq global] — compile-time indexed only
#pragma unroll
  for (int nq = 0; nq < 4; nq++) oacc[nq] = z4;

  // query norms (pre-scaled by KL2E) hoisted once
  float x2a[4];
#pragma unroll
  for (int nq = 0; nq < 4; nq++) x2a[nq] = x2v[qbase + nq * 16 + l15];

  // ---- initial stage: tile 0 -> ct8[0] ----
  {
    const uint4* src = (const uint4*)(ce8 + (size_t)(n0 + sr) * DIM + squ * 48);
    uint4* dst = (uint4*)&ct8[0][sr][squ * 48];
#pragma unroll
    for (int i = 0; i < 3; i++) dst[i] = src[i];
  }

#pragma unroll 1
  for (int c = 0; c < 4; ++c) {
    const int cb = c & 1;
    // issue-early: tile c+1 global loads fly during barrier + compute
    uint4 pf0, pf1, pf2;
    if (c < 3) {
      const uint4* src = (const uint4*)(ce8 + (size_t)(n0 + (c + 1) * 64 + sr) * DIM + squ * 48);
      pf0 = src[0]; pf1 = src[1]; pf2 = src[2];
    }
    __syncthreads();                           // ct8[cb] writes visible

    // Y B-frags: pre-packed bf16, lane-contiguous
    bf16x8 yf[2];
#pragma unroll
    for (int kb = 0; kb < 2; kb++)
      yf[kb] = *(const bf16x8*)&YB[((size_t)((slice * 8) + c * 2 + kb) * 64 + lane) * 8];
    // candidate norms (pre-scaled): broadcast f32x4 loads
    f32x4 c2r[4];
#pragma unroll
    for (int mc = 0; mc < 4; mc++)
      c2r[mc] = *(const f32x4*)&c2v[n0 + c * 64 + mc * 16 + q * 4];

    // two query-half passes: acc[4][2] each (32 AGPR, reused)
#pragma unroll
    for (int nqh = 0; nqh < 2; nqh++) {
      f32x4 acc[4][2];         // [mc][j], global nq = nqh*2 + j
#pragma unroll
      for (int mc = 0; mc < 4; mc++)
#pragma unroll
        for (int j = 0; j < 2; j++) acc[mc][j] = z4;

#pragma unroll 2
      for (int kk = 0; kk < 192; kk += 32) {
        long a[4], b[2];
#pragma unroll
        for (int mc = 0; mc < 4; mc++)
          a[mc] = *(const long*)&ct8[cb][mc * 16 + l15][kk + q * 8];
        const unsigned char* xp = &xe8[(size_t)(((kk >> 5) * 4 + q) * NQ + qbase + nqh * 32 + l15) * 8];
#pragma unroll
        for (int j = 0; j < 2; j++)
          b[j] = *(const long*)&xp[j * 128];
#pragma unroll
        for (int mc = 0; mc < 4; mc++)
#pragma unroll
          for (int j = 0; j < 2; j++)
            acc[mc][j] = __builtin_amdgcn_mfma_f32_16x16x32_fp8_fp8(a[mc], b[j], acc[mc][j], 0, 0, 0);
      }

      // epilogue: e = exp2(-sqrt(|K*d2|)); ET -> PV MFMA, per global nq
#pragma unroll
      for (int j = 0; j < 2; ++j) {
        const int nq = nqh * 2 + j;
#pragma unroll
        for (int mc = 0; mc < 4; mc++) {
          bf16x4 ev;
#pragma unroll
          for (int r = 0; r < 4; r++) {
            float d2 = __builtin_fmaf(N2KL2E, acc[mc][j][r], x2a[nq] + c2r[mc][r]);
            ev[r] = (bf16)__builtin_amdgcn_exp2f(-__builtin_amdgcn_sqrtf(__builtin_fabsf(d2)));
          }
          *(bf16x4*)&ET[w][l15][mc * 16 + q * 4] = ev;
        }
#pragma unroll
        for (int kb = 0; kb < 2; kb++) {
          bf16x8 a = *(const bf16x8*)&ET[w][l15][kb * 32 + q * 8];
          oacc[nq] = __builtin_amdgcn_mfma_f32_16x16x32_bf16(a, yf[kb], oacc[nq], 0, 0, 0);
        }
      }
    }

    // write prefetched tile c+1 into the other buffer (vmcnt wait here,
    // after compute — latency hidden). Safe: readers of that buffer
    // finished before this iteration's top barrier.
    if (c < 3) {
      uint4* dst = (uint4*)&ct8[cb ^ 1][sr][squ * 48];
      dst[0] = pf0; dst[1] = pf1; dst[2] = pf2;
    }
  }

  // ---- P write: stage in LDS (ct8 dead), then transposed records ----
  __syncthreads();
  float* Pst = (float*)&ct8[0][0][0];          // 256 q x 12 = 12.3 KB
  if (l15 < 11) {
#pragma unroll
    for (int nq = 0; nq < 4; nq++)
#pragma unroll
      for (int r = 0; r < 4; r++) {
        int lq = w * 64 + nq * 16 + q * 4 + r;
        Pst[lq * 12 + l15] = oacc[nq][r];
      }
  }
  __syncthreads();
  {
    const f32x4* Ps = (const f32x4*)Pst;
    float* Pb = P + ((size_t)qh * NSLICE + slice) * 12;
#pragma unroll
    for (int i = t; i < 768; i += 256) {
      int lq = i / 3, part = i % 3;            // record (qh+lq, slice)
      *(f32x4*)&Pb[(size_t)lq * NSLICE * 12 + part * 4] = Ps[i];
    }
  }
}

// ---------------- K4: combine (contiguous per-query P run) --------------
__global__ __launch_bounds__(512) void k_comb(const float* __restrict__ P,
                                              float* __restrict__ out) {
  __shared__ float red[8][11];
  const int t = threadIdx.x;
  const int qy = blockIdx.x;
  const int lane = t & 63, w = t >> 6;

  // record (qy, slice=t): contiguous 24 KB run per block
  const float* p = &P[((size_t)qy * NSLICE + t) * 12];
  f32x4 v0 = *(const f32x4*)&p[0];
  f32x4 v1 = *(const f32x4*)&p[4];
  f32x4 v2 = *(const f32x4*)&p[8];
  float s[11];
#pragma unroll
  for (int j = 0; j < 4; j++) s[j] = v0[j];
#pragma unroll
  for (int j = 0; j < 4; j++) s[4 + j] = v1[j];
#pragma unroll
  for (int j = 0; j < 3; j++) s[8 + j] = v2[j];
#pragma unroll
  for (int d = 1; d < 64; d <<= 1)
#pragma unroll
    for (int j = 0; j < 11; j++) s[j] += __shfl_xor(s[j], d);
  if (lane == 0)
#pragma unroll
    for (int j = 0; j < 11; j++) red[w][j] = s[j];
  __syncthreads();
  if (t < 10) {
    float o = 0.f, l = 0.f;
#pragma unroll
    for (int i = 0; i < 8; i++) { o += red[i][t]; l += red[i][10]; }
    out[qy * NY + t] = o / l;
  }
}

// ---------------- launcher ----------------
extern "C" void kernel_launch(void* const* d_in, const int* in_sizes, int n_in,
                              void* d_out, int out_size, void* d_ws, size_t ws_size,
                              hipStream_t stream) {
  (void)in_sizes; (void)n_in; (void)out_size; (void)ws_size;
  const float* x_num = (const float*)d_in[0];
  const int*   x_cat = (const int*)d_in[1];
  const float* c_num = (const float*)d_in[2];
  const int*   c_cat = (const int*)d_in[3];
  const float* c_y   = (const float*)d_in[4];
  const float* W_num = (const float*)d_in[5];
  const float* b_num = (const float*)d_in[6];
  const float* emb   = (const float*)d_in[7];
  const float* W1    = (const float*)d_in[8];
  const float* b1    = (const float*)d_in[9];
  const float* W2    = (const float*)d_in[10];
  const float* b2    = (const float*)d_in[11];
  float* out = (float*)d_out;

  char* ws = (char*)d_ws;
  unsigned char* W1B8 = (unsigned char*)(ws + OFF_W1B);
  unsigned char* W2B8 = (unsigned char*)(ws + OFF_W2B);
  unsigned char* xe8  = (unsigned char*)(ws + OFF_XE8);
  float* x2v = (float*)(ws + OFF_X2);
  unsigned char* ce8  = (unsigned char*)(ws + OFF_CE8);
  float* c2v = (float*)(ws + OFF_C2);
  float* P   = (float*)(ws + OFF_P);
  bf16*  YB  = (bf16*)(ws + OFF_YB);

  k_prep<<<dim3(384), dim3(256), 0, stream>>>(W1, W2, W1B8, W2B8);
  k_encode<<<dim3(2056 + 1024), dim3(256), 0, stream>>>(
      x_num, x_cat, c_num, c_cat, W_num, b_num, emb, b1, b2, W1B8, W2B8,
      ce8, xe8, x2v, c2v, c_y, YB);
  k_dist<<<dim3(2 * NSLICE), dim3(256), 0, stream>>>(xe8, x2v, ce8, c2v, YB, P);
  k_comb<<<dim3(NQ), dim3(512), 0, stream>>>(P, out);
}